// Round 9
// baseline (878.345 us; speedup 1.0000x reference)
//
#include <hip/hip_runtime.h>
#include <cstdint>

typedef unsigned short u16;
typedef unsigned int u32;
typedef __attribute__((ext_vector_type(8))) short short8;   // 8 bf16 (MFMA A/B frag)
typedef __attribute__((ext_vector_type(4))) float floatx4;  // MFMA C/D frag
typedef __attribute__((ext_vector_type(2))) float floatx2;  // packed f32 pair (v_pk_*_f32)

__device__ __forceinline__ float b2f(u16 u) {
    union { unsigned int i; float f; } c; c.i = ((unsigned int)u) << 16; return c.f;
}
__device__ __forceinline__ u16 f2b(float f) {
    union { float f; unsigned int i; } c; c.f = f;
    unsigned int u = c.i;
    u = u + 0x7FFFu + ((u >> 16) & 1u);   // RNE
    return (u16)(u >> 16);
}
__device__ __forceinline__ float u2f(u32 u) { union { u32 u; float f; } c; c.u = u; return c.f; }

// ---------------------------------------------------------------------------
// Fused Q/K/V projection GEMM. Y[m,n] = sum_k x[m,k]*W[n,k] + bias[n].
// grid (32, 24): which = blockIdx.y>>3 (0=q fp32, 1=k bf16, 2=v).
// For which==2 the 64x64 tile is transposed through LDS and stored CHUNK-MAJOR
// as vt[bh][chunk=c>>5][dt=d>>4][d&15][c&31] (bf16 hi + bf16 lo residual) so
// the attention PV step loads B-frags via one walking pointer + imm offsets.
// ---------------------------------------------------------------------------
__global__ __launch_bounds__(256) void gemm_qkv(
    const float* __restrict__ x,
    const float* __restrict__ Wq, const float* __restrict__ Wk, const float* __restrict__ Wv,
    const float* __restrict__ bq, const float* __restrict__ bk, const float* __restrict__ bv,
    float* __restrict__ qout, u16* __restrict__ kout,
    u16* __restrict__ vthi, u16* __restrict__ vtlo)
{
    __shared__ u16 xs[64 * 72];
    __shared__ u16 wsl[64 * 72];
    int tid = threadIdx.x;
    int lane = tid & 63;
    int wv = tid >> 6;
    int lo = lane & 15, hi = lane >> 4;
    int which = blockIdx.y >> 3;
    int m0 = blockIdx.x * 64, n0 = (blockIdx.y & 7) * 64;
    const float* W    = which == 0 ? Wq : (which == 1 ? Wk : Wv);
    const float* bias = which == 0 ? bq : (which == 1 ? bk : bv);

    floatx4 acc[4];
#pragma unroll
    for (int mt = 0; mt < 4; ++mt) acc[mt] = (floatx4){0.f, 0.f, 0.f, 0.f};

    for (int k0 = 0; k0 < 512; k0 += 64) {
        __syncthreads();
#pragma unroll
        for (int i = 0; i < 2; ++i) {
            int v = tid + i * 256;
            int row = v >> 3, c8 = (v & 7) * 8;
            const float* ap = x + (m0 + row) * 512 + k0 + c8;
            const float* wp = W + (n0 + row) * 512 + k0 + c8;
            float4 a0 = *(const float4*)(ap);
            float4 a1 = *(const float4*)(ap + 4);
            float4 w0 = *(const float4*)(wp);
            float4 w1v = *(const float4*)(wp + 4);
            union { u16 u[8]; uint4 q; } ca, cw;
            ca.u[0] = f2b(a0.x); ca.u[1] = f2b(a0.y); ca.u[2] = f2b(a0.z); ca.u[3] = f2b(a0.w);
            ca.u[4] = f2b(a1.x); ca.u[5] = f2b(a1.y); ca.u[6] = f2b(a1.z); ca.u[7] = f2b(a1.w);
            cw.u[0] = f2b(w0.x); cw.u[1] = f2b(w0.y); cw.u[2] = f2b(w0.z); cw.u[3] = f2b(w0.w);
            cw.u[4] = f2b(w1v.x); cw.u[5] = f2b(w1v.y); cw.u[6] = f2b(w1v.z); cw.u[7] = f2b(w1v.w);
            *(uint4*)(xs + row * 72 + c8)  = ca.q;
            *(uint4*)(wsl + row * 72 + c8) = cw.q;
        }
        __syncthreads();
#pragma unroll
        for (int ks = 0; ks < 2; ++ks) {
            short8 bfr = *(const short8*)(wsl + (wv * 16 + lo) * 72 + ks * 32 + hi * 8);
#pragma unroll
            for (int mt = 0; mt < 4; ++mt) {
                short8 afr = *(const short8*)(xs + (mt * 16 + lo) * 72 + ks * 32 + hi * 8);
                acc[mt] = __builtin_amdgcn_mfma_f32_16x16x32_bf16(afr, bfr, acc[mt], 0, 0, 0);
            }
        }
    }

    int n = n0 + wv * 16 + lo;
    float bv2 = bias[n];
    if (which == 2) {
        // transpose V tile through LDS; emit vt_hi/vt_lo bf16, chunk-major layout
        __syncthreads();                           // xs/wsl reuse: all waves done with MFMAs
        int nl = wv * 16 + lo;                     // local d
#pragma unroll
        for (int mt = 0; mt < 4; ++mt)
#pragma unroll
            for (int r = 0; r < 4; ++r) {
                int ml = mt * 16 + hi * 4 + r;     // local c
                float y = acc[mt][r] + bv2;
                u16 vh = f2b(y);
                u16 vl = f2b(y - b2f(vh));
                xs[nl * 72 + ml]  = vh;
                wsl[nl * 72 + ml] = vl;
            }
        __syncthreads();
        int row = tid >> 2, seg = (tid & 3) * 16;  // row = local d, seg = local c chunk
        int b = m0 >> 10, c0 = m0 & 1023, h2 = n0 >> 6;
        int cc = c0 + seg;                         // global c of this 16-piece (within one 32-chunk)
        size_t dst = (size_t)(b * 8 + h2) * 65536 + (cc >> 5) * 2048
                   + (row >> 4) * 512 + (row & 15) * 32 + (cc & 31);
        *(uint4*)(vthi + dst)     = *(uint4*)(xs  + row * 72 + seg);
        *(uint4*)(vthi + dst + 8) = *(uint4*)(xs  + row * 72 + seg + 8);
        *(uint4*)(vtlo + dst)     = *(uint4*)(wsl + row * 72 + seg);
        *(uint4*)(vtlo + dst + 8) = *(uint4*)(wsl + row * 72 + seg + 8);
    } else {
        int h = n >> 6, dd = n & 63;
#pragma unroll
        for (int mt = 0; mt < 4; ++mt)
#pragma unroll
            for (int r = 0; r < 4; ++r) {
                int m = m0 + mt * 16 + hi * 4 + r;  // C/D: row=(lane>>4)*4+reg, col=lane&15
                float y = acc[mt][r] + bv2;
                int b = m >> 10, c = m & 1023;
                int idx = (((b * 8 + h) * 1024) + c) * 64 + dd;
                if (which == 0) qout[idx] = y;
                else            kout[idx] = f2b(y);
            }
    }
}

// ---------------------------------------------------------------------------
// Output GEMM: Y[m,n] = sum_k A[m,k]*Wo[n,k] + bo[n], fp32 out, [m*512+n].
// ---------------------------------------------------------------------------
__global__ __launch_bounds__(256) void gemm_out(
    const float* __restrict__ A, const float* __restrict__ W, const float* __restrict__ bias,
    float* __restrict__ outf)
{
    __shared__ u16 xs[64 * 72];
    __shared__ u16 wsl[64 * 72];
    int tid = threadIdx.x;
    int lane = tid & 63;
    int wv = tid >> 6;
    int lo = lane & 15, hi = lane >> 4;
    int m0 = blockIdx.x * 64, n0 = blockIdx.y * 64;

    floatx4 acc[4];
#pragma unroll
    for (int mt = 0; mt < 4; ++mt) acc[mt] = (floatx4){0.f, 0.f, 0.f, 0.f};

    for (int k0 = 0; k0 < 512; k0 += 64) {
        __syncthreads();
#pragma unroll
        for (int i = 0; i < 2; ++i) {
            int v = tid + i * 256;
            int row = v >> 3, c8 = (v & 7) * 8;
            const float* ap = A + (m0 + row) * 512 + k0 + c8;
            const float* wp = W + (n0 + row) * 512 + k0 + c8;
            float4 a0 = *(const float4*)(ap);
            float4 a1 = *(const float4*)(ap + 4);
            float4 w0 = *(const float4*)(wp);
            float4 w1v = *(const float4*)(wp + 4);
            union { u16 u[8]; uint4 q; } ca, cw;
            ca.u[0] = f2b(a0.x); ca.u[1] = f2b(a0.y); ca.u[2] = f2b(a0.z); ca.u[3] = f2b(a0.w);
            ca.u[4] = f2b(a1.x); ca.u[5] = f2b(a1.y); ca.u[6] = f2b(a1.z); ca.u[7] = f2b(a1.w);
            cw.u[0] = f2b(w0.x); cw.u[1] = f2b(w0.y); cw.u[2] = f2b(w0.z); cw.u[3] = f2b(w0.w);
            cw.u[4] = f2b(w1v.x); cw.u[5] = f2b(w1v.y); cw.u[6] = f2b(w1v.z); cw.u[7] = f2b(w1v.w);
            *(uint4*)(xs + row * 72 + c8)  = ca.q;
            *(uint4*)(wsl + row * 72 + c8) = cw.q;
        }
        __syncthreads();
#pragma unroll
        for (int ks = 0; ks < 2; ++ks) {
            short8 bfr = *(const short8*)(wsl + (wv * 16 + lo) * 72 + ks * 32 + hi * 8);
#pragma unroll
            for (int mt = 0; mt < 4; ++mt) {
                short8 afr = *(const short8*)(xs + (mt * 16 + lo) * 72 + ks * 32 + hi * 8);
                acc[mt] = __builtin_amdgcn_mfma_f32_16x16x32_bf16(afr, bfr, acc[mt], 0, 0, 0);
            }
        }
    }

    int n = n0 + wv * 16 + lo;
    float bv = bias[n];
#pragma unroll
    for (int mt = 0; mt < 4; ++mt)
#pragma unroll
        for (int r = 0; r < 4; ++r) {
            int m = m0 + mt * 16 + hi * 4 + r;
            outf[m * 512 + n] = acc[mt][r] + bv;
        }
}

// ---------------------------------------------------------------------------
// Fused second-order attention, v21 = v20 structure (independent waves, zero
// barriers, chunk-major V^T) with the register economy FIXED instead of
// squeezed (v19/v20 post-mortem: the 128-reg tier from __launch_bounds__(256,4)
// forced 50-84 MB of scratch; occupancy bought with spills is fake):
//  (1) __launch_bounds__(256, 3): 170-reg budget, zero spill, 3 waves/SIMD.
//  (2) K DOUBLE-BUFFER (bfA/bfB): chunk j+2's loads issue in chunk j's mt=3
//      slot (same in-place trick) -> load-to-use distance = full chunk+tail
//      (~580 cyc) > L2 latency. The per-chunk-boundary K stall (the ~40%
//      idle of v17/v18) is covered for the first time.
//  (3) V-lo loads hoisted to right after the scoring loop (~250 cyc cover).
// Math byte-identical to v20 (passed, absmax 7.3e-4). Chunk body is a macro
// so both K buffers are statically named (no runtime-indexed arrays).
// ---------------------------------------------------------------------------
#define CHUNK_STEP(BF)                                                         \
    {                                                                          \
        uint4 vh0 = *(const uint4*)(vph);                                      \
        uint4 vh1 = *(const uint4*)(vph + 512);                                \
        uint4 vh2 = *(const uint4*)(vph + 1024);                               \
        uint4 vh3 = *(const uint4*)(vph + 1536);                               \
        floatx2 s0v = (floatx2){0.f, 0.f};                                     \
        floatx2 s1v = (floatx2){0.f, 0.f};                                     \
        floatx4 aP[2], aN[2];                                                  \
        aP[0] = __builtin_amdgcn_mfma_f32_16x16x32_bf16(af[0][0], BF[0][0], Z, 0, 0, 0); \
        aP[0] = __builtin_amdgcn_mfma_f32_16x16x32_bf16(af[0][1], BF[0][1], aP[0], 0, 0, 0); \
        aP[1] = __builtin_amdgcn_mfma_f32_16x16x32_bf16(af[0][0], BF[1][0], Z, 0, 0, 0); \
        aP[1] = __builtin_amdgcn_mfma_f32_16x16x32_bf16(af[0][1], BF[1][1], aP[1], 0, 0, 0); \
        _Pragma("unroll")                                                      \
        for (int mt = 0; mt < 4; ++mt) {                                       \
            if (mt < 3) {                                                      \
                aN[0] = __builtin_amdgcn_mfma_f32_16x16x32_bf16(af[mt + 1][0], BF[0][0], Z, 0, 0, 0); \
                aN[0] = __builtin_amdgcn_mfma_f32_16x16x32_bf16(af[mt + 1][1], BF[0][1], aN[0], 0, 0, 0); \
                aN[1] = __builtin_amdgcn_mfma_f32_16x16x32_bf16(af[mt + 1][0], BF[1][0], Z, 0, 0, 0); \
                aN[1] = __builtin_amdgcn_mfma_f32_16x16x32_bf16(af[mt + 1][1], BF[1][1], aN[1], 0, 0, 0); \
            } else {                                                           \
                /* last BF use was mt=2's aN MFMAs: reload in place for j+2 */ \
                uint4 k00 = *(const uint4*)(kc);                               \
                uint4 k01 = *(const uint4*)(kc + 32);                          \
                uint4 k10 = *(const uint4*)(kc + 1024);                        \
                uint4 k11 = *(const uint4*)(kc + 1056);                        \
                BF[0][0] = *(short8*)&k00; BF[0][1] = *(short8*)&k01;          \
                BF[1][0] = *(short8*)&k10; BF[1][1] = *(short8*)&k11;          \
                kc += 2048;                                                    \
            }                                                                  \
            _Pragma("unroll")                                                  \
            for (int h2 = 0; h2 < 2; ++h2) {                                   \
                u32 wp = wcp[mt][h2];                                          \
                floatx2 wv2 = (floatx2){u2f(wp << 16), u2f(wp & 0xFFFF0000u)}; \
                u32 qp = qpp[mt][h2];                                          \
                floatx2 qv = (floatx2){u2f(qp << 16), u2f(qp & 0xFFFF0000u)};  \
                _Pragma("unroll")                                              \
                for (int t = 0; t < 2; ++t) {                                  \
                    floatx2 x = (floatx2){aP[t][h2 * 2 + 0], aP[t][h2 * 2 + 1]} + qv; \
                    floatx2 ex = (floatx2){__builtin_amdgcn_exp2f(x.x),        \
                                           __builtin_amdgcn_exp2f(x.y)};       \
                    floatx2 a = ex + 1.0f;                                     \
                    float rc = __builtin_amdgcn_rcpf(a.x * a.y);               \
                    floatx2 sw = (floatx2){a.y, a.x};                          \
                    floatx2 contrib = (x * wv2) * (sw * rc);                   \
                    if (t == 0) s0v += contrib; else s1v += contrib;           \
                }                                                              \
            }                                                                  \
            aP[0] = aN[0];                                                     \
            aP[1] = aN[1];                                                     \
        }                                                                      \
        /* V-lo issued here: ~250 cyc of tail+PV-hi before first use */        \
        const u16* vpl = vph + (1u << 20);                                     \
        uint4 vl0 = *(const uint4*)(vpl);                                      \
        uint4 vl1 = *(const uint4*)(vpl + 512);                                \
        uint4 vl2 = *(const uint4*)(vpl + 1024);                               \
        uint4 vl3 = *(const uint4*)(vpl + 1536);                               \
        float s0 = s0v.x + s0v.y, s1 = s1v.x + s1v.y;                          \
        s0 += __shfl_xor(s0, 16); s0 += __shfl_xor(s0, 32);                    \
        s1 += __shfl_xor(s1, 16); s1 += __shfl_xor(s1, 32);                    \
        float p0 = __builtin_amdgcn_exp2f(s0 - 16.0f);                         \
        float p1 = __builtin_amdgcn_exp2f(s1 - 16.0f);                         \
        u16 ph0 = f2b(p0);                                                     \
        u16 ph1 = f2b(p1);                                                     \
        l_run += b2f(ph0) + b2f(ph1);                                          \
        if (lane < 16) { psw[lo] = ph0; psw[16 + lo] = ph1; }                  \
        short8 pf = *(const short8*)(psw + hi * 8);                            \
        pv[0] = __builtin_amdgcn_mfma_f32_16x16x32_bf16(pf, *(short8*)&vh0, pv[0], 0, 0, 0); \
        pv[1] = __builtin_amdgcn_mfma_f32_16x16x32_bf16(pf, *(short8*)&vh1, pv[1], 0, 0, 0); \
        pv[2] = __builtin_amdgcn_mfma_f32_16x16x32_bf16(pf, *(short8*)&vh2, pv[2], 0, 0, 0); \
        pv[3] = __builtin_amdgcn_mfma_f32_16x16x32_bf16(pf, *(short8*)&vh3, pv[3], 0, 0, 0); \
        pv[0] = __builtin_amdgcn_mfma_f32_16x16x32_bf16(pf, *(short8*)&vl0, pv[0], 0, 0, 0); \
        pv[1] = __builtin_amdgcn_mfma_f32_16x16x32_bf16(pf, *(short8*)&vl1, pv[1], 0, 0, 0); \
        pv[2] = __builtin_amdgcn_mfma_f32_16x16x32_bf16(pf, *(short8*)&vl2, pv[2], 0, 0, 0); \
        pv[3] = __builtin_amdgcn_mfma_f32_16x16x32_bf16(pf, *(short8*)&vl3, pv[3], 0, 0, 0); \
        vph += 2048;                                                           \
    }

__global__ __launch_bounds__(256, 3) void attn21(
    const float* __restrict__ qf, const u16* __restrict__ kb,
    const u16* __restrict__ vthi, const u16* __restrict__ vtlo,
    const float* __restrict__ w1, const float* __restrict__ b1, const float* __restrict__ w2,
    float* __restrict__ ao)
{
    __shared__ float q_l[4 * 64];
    __shared__ __align__(16) u16 p_sw[4 * 32];     // per-wave P staging (64 B each)
    int tid = threadIdx.x;
    int lane = tid & 63;
    int wv = tid >> 6;
    int lo = lane & 15, hi = lane >> 4;
    int bh = blockIdx.x >> 8;                      // 0..15 = b*8+h
    int qbase = (blockIdx.x & 255) << 2;           // block's first query
    int qi = qbase | wv;                           // this wave's query

    const float NA = -2.45546696f;                 // -1.702 * log2(e)

    q_l[wv * 64 + lane] = qf[(bh * 1024 + qi) * 64 + lane];   // wave-private segment

    // qp[e]+b1[e] at lane=e
    float qpacc = b1[lane];
#pragma unroll
    for (int d8 = 0; d8 < 64; d8 += 8) {
        float4 wa = *(const float4*)(w1 + lane * 192 + d8);
        float4 wb = *(const float4*)(w1 + lane * 192 + d8 + 4);
        const float* q8 = q_l + wv * 64 + d8;      // wave-uniform broadcast reads
        qpacc = __builtin_fmaf(q8[0], wa.x, qpacc);
        qpacc = __builtin_fmaf(q8[1], wa.y, qpacc);
        qpacc = __builtin_fmaf(q8[2], wa.z, qpacc);
        qpacc = __builtin_fmaf(q8[3], wa.w, qpacc);
        qpacc = __builtin_fmaf(q8[4], wb.x, qpacc);
        qpacc = __builtin_fmaf(q8[5], wb.y, qpacc);
        qpacc = __builtin_fmaf(q8[6], wb.z, qpacc);
        qpacc = __builtin_fmaf(q8[7], wb.w, qpacc);
    }
    qpacc *= NA;                                   // qp' = c * (qp + b1)

    // w2c packed: wc' = w2[e] * (1/8)*log2e / c ; qp' packed the same way
    u32 wcp[4][2];
    u32 qpp[4][2];
    float w2row = w2[lane] * -0.07344288f;
#pragma unroll
    for (int mt = 0; mt < 4; ++mt)
#pragma unroll
        for (int h2 = 0; h2 < 2; ++h2) {
            int e0 = mt * 16 + hi * 4 + h2 * 2;
            u32 wlo = (u32)f2b(__shfl(w2row, e0));
            u32 whi = (u32)f2b(__shfl(w2row, e0 + 1));
            wcp[mt][h2] = (whi << 16) | wlo;
            u32 qlo = (u32)f2b(__shfl(qpacc, e0));
            u32 qhi = (u32)f2b(__shfl(qpacc, e0 + 1));
            qpp[mt][h2] = (qhi << 16) | qlo;
        }

    // q pieces for frag build: qv2[ks][j] = q[ks*32 + hi*8 + j]
    float qv2[2][8];
#pragma unroll
    for (int ks = 0; ks < 2; ++ks)
#pragma unroll
        for (int j = 0; j < 8; ++j)
            qv2[ks][j] = q_l[wv * 64 + ks * 32 + hi * 8 + j];

    // A-frags: c * qw'[e = mt*16+lo][dd = ks*32 + hi*8 + j], bf16
    short8 af[4][2];
#pragma unroll
    for (int mt = 0; mt < 4; ++mt) {
        const float* wr = w1 + (mt * 16 + lo) * 192;
#pragma unroll
        for (int ks = 0; ks < 2; ++ks) {
            int dd0 = ks * 32 + hi * 8;
            float4 a0 = *(const float4*)(wr + 128 + dd0);
            float4 a1 = *(const float4*)(wr + 128 + dd0 + 4);
            float4 k0 = *(const float4*)(wr + 64 + dd0);
            float4 k1 = *(const float4*)(wr + 64 + dd0 + 4);
            union { u16 u[8]; short8 s; } cv;
            cv.u[0] = f2b(NA * __builtin_fmaf(qv2[ks][0], a0.x, k0.x));
            cv.u[1] = f2b(NA * __builtin_fmaf(qv2[ks][1], a0.y, k0.y));
            cv.u[2] = f2b(NA * __builtin_fmaf(qv2[ks][2], a0.z, k0.z));
            cv.u[3] = f2b(NA * __builtin_fmaf(qv2[ks][3], a0.w, k0.w));
            cv.u[4] = f2b(NA * __builtin_fmaf(qv2[ks][4], a1.x, k1.x));
            cv.u[5] = f2b(NA * __builtin_fmaf(qv2[ks][5], a1.y, k1.y));
            cv.u[6] = f2b(NA * __builtin_fmaf(qv2[ks][6], a1.z, k1.z));
            cv.u[7] = f2b(NA * __builtin_fmaf(qv2[ks][7], a1.w, k1.w));
            af[mt][ks] = cv.s;
        }
    }

    float l_run = 0.f;
    floatx4 pv[4];
#pragma unroll
    for (int dt = 0; dt < 4; ++dt) pv[dt] = (floatx4){0.f, 0.f, 0.f, 0.f};
    const floatx4 Z = (floatx4){0.f, 0.f, 0.f, 0.f};

    // walking per-lane K pointer (advances 2048 u16 per load; imm offsets
    // {0,32,1024,1056} u16). Final over-runs land in vthi region, unused.
    const u16* kc = kb + bh * 65536 + lo * 64 + hi * 8;
    // walking V^T hi pointer, chunk-major layout: +2048 u16/chunk, imm dt*512.
    // lo pointer derived per chunk: vtlo = vthi + (1<<20) u16 (layout const).
    const u16* vph = vthi + bh * 65536 + lo * 32 + hi * 8;
    u16* psw = p_sw + wv * 32;                     // this wave's staging plane

    // prologue: chunk 0 -> bfA, chunk 1 -> bfB; kc then points at chunk 2
    short8 bfA[2][2], bfB[2][2];
    {
        uint4 k00 = *(const uint4*)(kc);
        uint4 k01 = *(const uint4*)(kc + 32);
        uint4 k10 = *(const uint4*)(kc + 1024);
        uint4 k11 = *(const uint4*)(kc + 1056);
        bfA[0][0] = *(short8*)&k00; bfA[0][1] = *(short8*)&k01;
        bfA[1][0] = *(short8*)&k10; bfA[1][1] = *(short8*)&k11;
        kc += 2048;
        uint4 m00 = *(const uint4*)(kc);
        uint4 m01 = *(const uint4*)(kc + 32);
        uint4 m10 = *(const uint4*)(kc + 1024);
        uint4 m11 = *(const uint4*)(kc + 1056);
        bfB[0][0] = *(short8*)&m00; bfB[0][1] = *(short8*)&m01;
        bfB[1][0] = *(short8*)&m10; bfB[1][1] = *(short8*)&m11;
        kc += 2048;
    }

    for (int g2 = 0; g2 < 16; ++g2) {
        CHUNK_STEP(bfA)                            // even chunk; reloads bfA for +2
        CHUNK_STEP(bfB)                            // odd chunk;  reloads bfB for +2
    }

    // per-wave l: sum over the 16 lo lanes (values hi-duplicated)
    float l = l_run;
    l += __shfl_xor(l, 1); l += __shfl_xor(l, 2);
    l += __shfl_xor(l, 4); l += __shfl_xor(l, 8);
    float rl = __builtin_amdgcn_rcpf(l);

    if (hi == 0) {                                 // D row 0 lives at lanes 0..15, reg 0
        int b = bh >> 3, h = bh & 7;
        float* dst = ao + ((size_t)(b * 1024 + qi) * 512) + h * 64 + lo;
        dst[0]  = pv[0][0] * rl;
        dst[16] = pv[1][0] * rl;
        dst[32] = pv[2][0] * rl;
        dst[48] = pv[3][0] * rl;
    }
}
#undef CHUNK_STEP

// ---------------------------------------------------------------------------
extern "C" void kernel_launch(void* const* d_in, const int* in_sizes, int n_in,
                              void* d_out, int out_size, void* d_ws, size_t ws_size,
                              hipStream_t stream)
{
    (void)in_sizes; (void)n_in; (void)out_size; (void)ws_size;
    const float* x  = (const float*)d_in[0];
    const float* Wq = (const float*)d_in[1];
    const float* bq = (const float*)d_in[2];
    const float* Wk = (const float*)d_in[3];
    const float* bk = (const float*)d_in[4];
    const float* Wv = (const float*)d_in[5];
    const float* bv = (const float*)d_in[6];
    const float* w1 = (const float*)d_in[7];
    const float* b1 = (const float*)d_in[8];
    const float* w2 = (const float*)d_in[9];
    // d_in[10] = b2: scalar shift of all scores -> softmax-invariant -> unused
    const float* Wo = (const float*)d_in[11];
    const float* bo = (const float*)d_in[12];

    char* ws = (char*)d_ws;
    float* q_ws = (float*)(ws);               // 4 MB fp32 (b,h,c,d)
    u16*   k_ws = (u16*)(ws + (4u << 20));    // 2 MB bf16 (b,h,c,d)
    u16*   vthi = (u16*)(ws + (6u << 20));    // 2 MB bf16 V^T hi, chunk-major
    u16*   vtlo = (u16*)(ws + (8u << 20));    // 2 MB bf16 V^T lo, chunk-major (MUST stay vthi+2MB)
    float* a_ws = (float*)(ws + (10u << 20)); // 4 MB fp32 (b,c,D)

    dim3 blk(256);
    hipLaunchKernelGGL(gemm_qkv, dim3(32, 24), blk, 0, stream,
                       x, Wq, Wk, Wv, bq, bk, bv, q_ws, k_ws, vthi, vtlo);
    hipLaunchKernelGGL(attn21, dim3(4096), blk, 0, stream,
                       q_ws, k_ws, vthi, vtlo, w1, b1, w2, a_ws);
    hipLaunchKernelGGL(gemm_out, dim3(32, 8), blk, 0, stream, a_ws, Wo, bo, (float*)d_out);
}

// Round 10
// 675.203 us; speedup vs baseline: 1.3009x; 1.3009x over previous
//
#include <hip/hip_runtime.h>
#include <cstdint>

typedef unsigned short u16;
typedef unsigned int u32;
typedef __attribute__((ext_vector_type(8))) short short8;   // 8 bf16 (MFMA A/B frag)
typedef __attribute__((ext_vector_type(4))) float floatx4;  // MFMA C/D frag
typedef __attribute__((ext_vector_type(2))) float floatx2;  // packed f32 pair (v_pk_*_f32)

__device__ __forceinline__ float b2f(u16 u) {
    union { unsigned int i; float f; } c; c.i = ((unsigned int)u) << 16; return c.f;
}
__device__ __forceinline__ u16 f2b(float f) {
    union { float f; unsigned int i; } c; c.f = f;
    unsigned int u = c.i;
    u = u + 0x7FFFu + ((u >> 16) & 1u);   // RNE
    return (u16)(u >> 16);
}
__device__ __forceinline__ float u2f(u32 u) { union { u32 u; float f; } c; c.u = u; return c.f; }

// ---------------------------------------------------------------------------
// Fused Q/K/V projection GEMM. Y[m,n] = sum_k x[m,k]*W[n,k] + bias[n].
// grid (32, 24): which = blockIdx.y>>3 (0=q fp32, 1=k bf16, 2=v -> vt hi/lo bf16 transposed).
// ---------------------------------------------------------------------------
__global__ __launch_bounds__(256) void gemm_qkv(
    const float* __restrict__ x,
    const float* __restrict__ Wq, const float* __restrict__ Wk, const float* __restrict__ Wv,
    const float* __restrict__ bq, const float* __restrict__ bk, const float* __restrict__ bv,
    float* __restrict__ qout, u16* __restrict__ kout,
    u16* __restrict__ vthi, u16* __restrict__ vtlo)
{
    __shared__ u16 xs[64 * 72];
    __shared__ u16 wsl[64 * 72];
    int tid = threadIdx.x;
    int lane = tid & 63;
    int wv = tid >> 6;
    int lo = lane & 15, hi = lane >> 4;
    int which = blockIdx.y >> 3;
    int m0 = blockIdx.x * 64, n0 = (blockIdx.y & 7) * 64;
    const float* W    = which == 0 ? Wq : (which == 1 ? Wk : Wv);
    const float* bias = which == 0 ? bq : (which == 1 ? bk : bv);

    floatx4 acc[4];
#pragma unroll
    for (int mt = 0; mt < 4; ++mt) acc[mt] = (floatx4){0.f, 0.f, 0.f, 0.f};

    for (int k0 = 0; k0 < 512; k0 += 64) {
        __syncthreads();
#pragma unroll
        for (int i = 0; i < 2; ++i) {
            int v = tid + i * 256;
            int row = v >> 3, c8 = (v & 7) * 8;
            const float* ap = x + (m0 + row) * 512 + k0 + c8;
            const float* wp = W + (n0 + row) * 512 + k0 + c8;
            float4 a0 = *(const float4*)(ap);
            float4 a1 = *(const float4*)(ap + 4);
            float4 w0 = *(const float4*)(wp);
            float4 w1v = *(const float4*)(wp + 4);
            union { u16 u[8]; uint4 q; } ca, cw;
            ca.u[0] = f2b(a0.x); ca.u[1] = f2b(a0.y); ca.u[2] = f2b(a0.z); ca.u[3] = f2b(a0.w);
            ca.u[4] = f2b(a1.x); ca.u[5] = f2b(a1.y); ca.u[6] = f2b(a1.z); ca.u[7] = f2b(a1.w);
            cw.u[0] = f2b(w0.x); cw.u[1] = f2b(w0.y); cw.u[2] = f2b(w0.z); cw.u[3] = f2b(w0.w);
            cw.u[4] = f2b(w1v.x); cw.u[5] = f2b(w1v.y); cw.u[6] = f2b(w1v.z); cw.u[7] = f2b(w1v.w);
            *(uint4*)(xs + row * 72 + c8)  = ca.q;
            *(uint4*)(wsl + row * 72 + c8) = cw.q;
        }
        __syncthreads();
#pragma unroll
        for (int ks = 0; ks < 2; ++ks) {
            short8 bfr = *(const short8*)(wsl + (wv * 16 + lo) * 72 + ks * 32 + hi * 8);
#pragma unroll
            for (int mt = 0; mt < 4; ++mt) {
                short8 afr = *(const short8*)(xs + (mt * 16 + lo) * 72 + ks * 32 + hi * 8);
                acc[mt] = __builtin_amdgcn_mfma_f32_16x16x32_bf16(afr, bfr, acc[mt], 0, 0, 0);
            }
        }
    }

    int n = n0 + wv * 16 + lo;
    float bv2 = bias[n];
    if (which == 2) {
        // transpose V tile through LDS; emit vt_hi/vt_lo bf16 [bh][d][c]
        __syncthreads();                           // xs/wsl reuse: all waves done with MFMAs
        int nl = wv * 16 + lo;                     // local d
#pragma unroll
        for (int mt = 0; mt < 4; ++mt)
#pragma unroll
            for (int r = 0; r < 4; ++r) {
                int ml = mt * 16 + hi * 4 + r;     // local c
                float y = acc[mt][r] + bv2;
                u16 vh = f2b(y);
                u16 vl = f2b(y - b2f(vh));
                xs[nl * 72 + ml]  = vh;
                wsl[nl * 72 + ml] = vl;
            }
        __syncthreads();
        int row = tid >> 2, seg = (tid & 3) * 16;  // row = local d, seg = local c chunk
        int b = m0 >> 10, c0 = m0 & 1023, h2 = n0 >> 6;
        size_t dst = ((size_t)((b * 8 + h2) * 64 + row)) * 1024 + c0 + seg;
        *(uint4*)(vthi + dst)     = *(uint4*)(xs  + row * 72 + seg);
        *(uint4*)(vthi + dst + 8) = *(uint4*)(xs  + row * 72 + seg + 8);
        *(uint4*)(vtlo + dst)     = *(uint4*)(wsl + row * 72 + seg);
        *(uint4*)(vtlo + dst + 8) = *(uint4*)(wsl + row * 72 + seg + 8);
    } else {
        int h = n >> 6, dd = n & 63;
#pragma unroll
        for (int mt = 0; mt < 4; ++mt)
#pragma unroll
            for (int r = 0; r < 4; ++r) {
                int m = m0 + mt * 16 + hi * 4 + r;  // C/D: row=(lane>>4)*4+reg, col=lane&15
                float y = acc[mt][r] + bv2;
                int b = m >> 10, c = m & 1023;
                int idx = (((b * 8 + h) * 1024) + c) * 64 + dd;
                if (which == 0) qout[idx] = y;
                else            kout[idx] = f2b(y);
            }
    }
}

// ---------------------------------------------------------------------------
// Output GEMM: Y[m,n] = sum_k A[m,k]*Wo[n,k] + bo[n], fp32 out, [m*512+n].
// ---------------------------------------------------------------------------
__global__ __launch_bounds__(256) void gemm_out(
    const float* __restrict__ A, const float* __restrict__ W, const float* __restrict__ bias,
    float* __restrict__ outf)
{
    __shared__ u16 xs[64 * 72];
    __shared__ u16 wsl[64 * 72];
    int tid = threadIdx.x;
    int lane = tid & 63;
    int wv = tid >> 6;
    int lo = lane & 15, hi = lane >> 4;
    int m0 = blockIdx.x * 64, n0 = blockIdx.y * 64;

    floatx4 acc[4];
#pragma unroll
    for (int mt = 0; mt < 4; ++mt) acc[mt] = (floatx4){0.f, 0.f, 0.f, 0.f};

    for (int k0 = 0; k0 < 512; k0 += 64) {
        __syncthreads();
#pragma unroll
        for (int i = 0; i < 2; ++i) {
            int v = tid + i * 256;
            int row = v >> 3, c8 = (v & 7) * 8;
            const float* ap = A + (m0 + row) * 512 + k0 + c8;
            const float* wp = W + (n0 + row) * 512 + k0 + c8;
            float4 a0 = *(const float4*)(ap);
            float4 a1 = *(const float4*)(ap + 4);
            float4 w0 = *(const float4*)(wp);
            float4 w1v = *(const float4*)(wp + 4);
            union { u16 u[8]; uint4 q; } ca, cw;
            ca.u[0] = f2b(a0.x); ca.u[1] = f2b(a0.y); ca.u[2] = f2b(a0.z); ca.u[3] = f2b(a0.w);
            ca.u[4] = f2b(a1.x); ca.u[5] = f2b(a1.y); ca.u[6] = f2b(a1.z); ca.u[7] = f2b(a1.w);
            cw.u[0] = f2b(w0.x); cw.u[1] = f2b(w0.y); cw.u[2] = f2b(w0.z); cw.u[3] = f2b(w0.w);
            cw.u[4] = f2b(w1v.x); cw.u[5] = f2b(w1v.y); cw.u[6] = f2b(w1v.z); cw.u[7] = f2b(w1v.w);
            *(uint4*)(xs + row * 72 + c8)  = ca.q;
            *(uint4*)(wsl + row * 72 + c8) = cw.q;
        }
        __syncthreads();
#pragma unroll
        for (int ks = 0; ks < 2; ++ks) {
            short8 bfr = *(const short8*)(wsl + (wv * 16 + lo) * 72 + ks * 32 + hi * 8);
#pragma unroll
            for (int mt = 0; mt < 4; ++mt) {
                short8 afr = *(const short8*)(xs + (mt * 16 + lo) * 72 + ks * 32 + hi * 8);
                acc[mt] = __builtin_amdgcn_mfma_f32_16x16x32_bf16(afr, bfr, acc[mt], 0, 0, 0);
            }
        }
    }

    int n = n0 + wv * 16 + lo;
    float bv = bias[n];
#pragma unroll
    for (int mt = 0; mt < 4; ++mt)
#pragma unroll
        for (int r = 0; r < 4; ++r) {
            int m = m0 + mt * 16 + hi * 4 + r;
            outf[m * 512 + n] = acc[mt][r] + bv;
        }
}

// ---------------------------------------------------------------------------
// Fused second-order attention, v22 = v18 skeleton (4-wave block, group
// exchange, barrier per 128 keys -- the best no-spill structure, 497 us)
// plus the ONE piece of v19-v21 that fits the 128-reg tier:
//  (1) K PREFETCH DEPTH 2: bfA/bfB double buffer; chunk c's mt=3 slot
//      reloads its own buffer with chunk c+2 -> load-to-use distance
//      ~1.5 chunks (>600 cyc) >> L2 latency. Kills the chunk-top K stall
//      (the 41% idle signature of v17/v18).
//  (2) Paid for by folding the rank-1 qp' C-init (16 AGPRs + 4 setup MFMAs)
//      into scoring as a packed bf16 add (qpp, +1 pk_add/pair) -- the exact
//      mechanism verified in v19/v20 (passed, absmax 7.3e-4).
// Budget audit: arch ~94 + acc ~24 < 128; slack ~10 (v18 had 0).
// Keeps __launch_bounds__(256,4) -- the only tier with sane allocation.
// ---------------------------------------------------------------------------
#define CHUNK_STEP(BF, CIDX)                                                   \
    {                                                                          \
        floatx2 s0v = (floatx2){0.f, 0.f};                                     \
        floatx2 s1v = (floatx2){0.f, 0.f};                                     \
        floatx4 aP[2], aN[2];                                                  \
        aP[0] = __builtin_amdgcn_mfma_f32_16x16x32_bf16(af[0][0], BF[0][0], Z, 0, 0, 0); \
        aP[0] = __builtin_amdgcn_mfma_f32_16x16x32_bf16(af[0][1], BF[0][1], aP[0], 0, 0, 0); \
        aP[1] = __builtin_amdgcn_mfma_f32_16x16x32_bf16(af[0][0], BF[1][0], Z, 0, 0, 0); \
        aP[1] = __builtin_amdgcn_mfma_f32_16x16x32_bf16(af[0][1], BF[1][1], aP[1], 0, 0, 0); \
        _Pragma("unroll")                                                      \
        for (int mt = 0; mt < 4; ++mt) {                                       \
            if (mt < 3) {                                                      \
                aN[0] = __builtin_amdgcn_mfma_f32_16x16x32_bf16(af[mt + 1][0], BF[0][0], Z, 0, 0, 0); \
                aN[0] = __builtin_amdgcn_mfma_f32_16x16x32_bf16(af[mt + 1][1], BF[0][1], aN[0], 0, 0, 0); \
                aN[1] = __builtin_amdgcn_mfma_f32_16x16x32_bf16(af[mt + 1][0], BF[1][0], Z, 0, 0, 0); \
                aN[1] = __builtin_amdgcn_mfma_f32_16x16x32_bf16(af[mt + 1][1], BF[1][1], aN[1], 0, 0, 0); \
            } else {                                                           \
                /* last BF use was mt=2's aN MFMAs: reload with chunk +2 */    \
                uint4 k00 = *(const uint4*)(kc);                               \
                uint4 k01 = *(const uint4*)(kc + 32);                          \
                uint4 k10 = *(const uint4*)(kc + 1024);                        \
                uint4 k11 = *(const uint4*)(kc + 1056);                        \
                BF[0][0] = *(short8*)&k00; BF[0][1] = *(short8*)&k01;          \
                BF[1][0] = *(short8*)&k10; BF[1][1] = *(short8*)&k11;          \
                kc += 2048;                                                    \
            }                                                                  \
            _Pragma("unroll")                                                  \
            for (int h2 = 0; h2 < 2; ++h2) {                                   \
                u32 wp = wcp[mt][h2];                                          \
                floatx2 wv2 = (floatx2){u2f(wp << 16), u2f(wp & 0xFFFF0000u)}; \
                u32 qp = qpp[mt][h2];                                          \
                floatx2 qv = (floatx2){u2f(qp << 16), u2f(qp & 0xFFFF0000u)};  \
                _Pragma("unroll")                                              \
                for (int t = 0; t < 2; ++t) {                                  \
                    floatx2 x = (floatx2){aP[t][h2 * 2 + 0], aP[t][h2 * 2 + 1]} + qv; \
                    floatx2 ex = (floatx2){__builtin_amdgcn_exp2f(x.x),        \
                                           __builtin_amdgcn_exp2f(x.y)};       \
                    floatx2 a = ex + 1.0f;                                     \
                    float rc = __builtin_amdgcn_rcpf(a.x * a.y);               \
                    floatx2 sw = (floatx2){a.y, a.x};                          \
                    floatx2 contrib = (x * wv2) * (sw * rc);                   \
                    if (t == 0) s0v += contrib; else s1v += contrib;           \
                }                                                              \
            }                                                                  \
            aP[0] = aN[0];                                                     \
            aP[1] = aN[1];                                                     \
        }                                                                      \
        float s0 = s0v.x + s0v.y, s1 = s1v.x + s1v.y;                          \
        s0 += __shfl_xor(s0, 16); s0 += __shfl_xor(s0, 32);                    \
        s1 += __shfl_xor(s1, 16); s1 += __shfl_xor(s1, 32);                    \
        float p0 = __builtin_amdgcn_exp2f(s0 - 16.0f);                         \
        float p1 = __builtin_amdgcn_exp2f(s1 - 16.0f);                         \
        u16 ph0 = f2b(p0);                                                     \
        u16 ph1 = f2b(p1);                                                     \
        l_run += b2f(ph0) + b2f(ph1);                                          \
        u16* pw = gw + (CIDX) * 528;                                           \
        if (lane < 16) {                                                       \
            pw[((lo >> 3) * 16 + wv) * 8 + (lo & 7)] = ph0;                    \
            pw[((2 + (lo >> 3)) * 16 + wv) * 8 + (lo & 7)] = ph1;              \
        }                                                                      \
    }

__global__ __launch_bounds__(256, 4) void attn22(
    const float* __restrict__ qf, const u16* __restrict__ kb,
    const u16* __restrict__ vthi, const u16* __restrict__ vtlo,
    const float* __restrict__ w1, const float* __restrict__ b1, const float* __restrict__ w2,
    float* __restrict__ ao)
{
    __shared__ float q_l[4 * 64];
    __shared__ __align__(16) u16 plds[2 * 4 * 528];   // [dbuf][chunk plane 528][A-frag order]
    __shared__ float l_sh[4];
    int tid = threadIdx.x;
    int lane = tid & 63;
    int wv = tid >> 6;
    int lo = lane & 15, hi = lane >> 4;
    int bh = blockIdx.x >> 8;                      // 0..15 = b*8+h
    int qbase = (blockIdx.x & 255) << 2;           // block's first query
    int qi = qbase | wv;                           // this wave's query

    const float NA = -2.45546696f;                 // -1.702 * log2(e)

    // zero p-LDS once: A-frag rows q=4..15 must stay 0 so PV C rows 4..15 are clean
    for (int i = tid; i < 2112; i += 256) ((u32*)plds)[i] = 0;

    q_l[wv * 64 + lane] = qf[(bh * 1024 + qi) * 64 + lane];

    // qp[e]+b1[e] at lane=e
    float qpacc = b1[lane];
#pragma unroll
    for (int d8 = 0; d8 < 64; d8 += 8) {
        float4 wa = *(const float4*)(w1 + lane * 192 + d8);
        float4 wb = *(const float4*)(w1 + lane * 192 + d8 + 4);
        const float* q8 = q_l + wv * 64 + d8;      // wave-uniform broadcast reads
        qpacc = __builtin_fmaf(q8[0], wa.x, qpacc);
        qpacc = __builtin_fmaf(q8[1], wa.y, qpacc);
        qpacc = __builtin_fmaf(q8[2], wa.z, qpacc);
        qpacc = __builtin_fmaf(q8[3], wa.w, qpacc);
        qpacc = __builtin_fmaf(q8[4], wb.x, qpacc);
        qpacc = __builtin_fmaf(q8[5], wb.y, qpacc);
        qpacc = __builtin_fmaf(q8[6], wb.z, qpacc);
        qpacc = __builtin_fmaf(q8[7], wb.w, qpacc);
    }
    qpacc *= NA;                                   // qp' = c * (qp + b1)

    // w2c packed: wc' = w2[e] * (1/8)*log2e / c ; qp' packed the same way
    u32 wcp[4][2];
    u32 qpp[4][2];
    float w2row = w2[lane] * -0.07344288f;
#pragma unroll
    for (int mt = 0; mt < 4; ++mt)
#pragma unroll
        for (int h2 = 0; h2 < 2; ++h2) {
            int e0 = mt * 16 + hi * 4 + h2 * 2;
            u32 wlo = (u32)f2b(__shfl(w2row, e0));
            u32 whi = (u32)f2b(__shfl(w2row, e0 + 1));
            wcp[mt][h2] = (whi << 16) | wlo;
            u32 qlo = (u32)f2b(__shfl(qpacc, e0));
            u32 qhi = (u32)f2b(__shfl(qpacc, e0 + 1));
            qpp[mt][h2] = (qhi << 16) | qlo;
        }

    // q pieces for frag build: qv2[ks][j] = q[ks*32 + hi*8 + j]
    float qv2[2][8];
#pragma unroll
    for (int ks = 0; ks < 2; ++ks)
#pragma unroll
        for (int j = 0; j < 8; ++j)
            qv2[ks][j] = q_l[wv * 64 + ks * 32 + hi * 8 + j];

    // A-frags: c * qw'[e = mt*16+lo][dd = ks*32 + hi*8 + j], bf16
    short8 af[4][2];
#pragma unroll
    for (int mt = 0; mt < 4; ++mt) {
        const float* wr = w1 + (mt * 16 + lo) * 192;
#pragma unroll
        for (int ks = 0; ks < 2; ++ks) {
            int dd0 = ks * 32 + hi * 8;
            float4 a0 = *(const float4*)(wr + 128 + dd0);
            float4 a1 = *(const float4*)(wr + 128 + dd0 + 4);
            float4 k0 = *(const float4*)(wr + 64 + dd0);
            float4 k1 = *(const float4*)(wr + 64 + dd0 + 4);
            union { u16 u[8]; short8 s; } cv;
            cv.u[0] = f2b(NA * __builtin_fmaf(qv2[ks][0], a0.x, k0.x));
            cv.u[1] = f2b(NA * __builtin_fmaf(qv2[ks][1], a0.y, k0.y));
            cv.u[2] = f2b(NA * __builtin_fmaf(qv2[ks][2], a0.z, k0.z));
            cv.u[3] = f2b(NA * __builtin_fmaf(qv2[ks][3], a0.w, k0.w));
            cv.u[4] = f2b(NA * __builtin_fmaf(qv2[ks][4], a1.x, k1.x));
            cv.u[5] = f2b(NA * __builtin_fmaf(qv2[ks][5], a1.y, k1.y));
            cv.u[6] = f2b(NA * __builtin_fmaf(qv2[ks][6], a1.z, k1.z));
            cv.u[7] = f2b(NA * __builtin_fmaf(qv2[ks][7], a1.w, k1.w));
            af[mt][ks] = cv.s;
        }
    }

    // zero-init must complete block-wide before any wave's first p-write
    __syncthreads();

    float l_run = 0.f;
    floatx4 pvacc = (floatx4){0.f, 0.f, 0.f, 0.f};   // out[q=row 0..3][d = wv*16+col]
    const floatx4 Z = (floatx4){0.f, 0.f, 0.f, 0.f};

    // walking per-lane K pointer (advances 2048 u16 per reload; imm offsets
    // {0,32,1024,1056} u16). Final over-runs land in vthi region, unused.
    const u16* kc = kb + bh * 65536 + lo * 64 + hi * 8;
    // V^T B-frag bases: this wave's d-tile row = wv*16+lo, k-offset hi*8;
    // walking pointer +128 u16/group, imm offsets c*32.
    const u16* vhp = vthi + bh * 65536 + (wv * 16 + lo) * 1024 + hi * 8;
    const u16* vlp = vtlo + bh * 65536 + (wv * 16 + lo) * 1024 + hi * 8;

    // prologue: chunk 0 -> bfA, chunk 1 -> bfB; kc then points at chunk 2
    short8 bfA[2][2], bfB[2][2];
    {
        uint4 k00 = *(const uint4*)(kc);
        uint4 k01 = *(const uint4*)(kc + 32);
        uint4 k10 = *(const uint4*)(kc + 1024);
        uint4 k11 = *(const uint4*)(kc + 1056);
        bfA[0][0] = *(short8*)&k00; bfA[0][1] = *(short8*)&k01;
        bfA[1][0] = *(short8*)&k10; bfA[1][1] = *(short8*)&k11;
        kc += 2048;
        uint4 m00 = *(const uint4*)(kc);
        uint4 m01 = *(const uint4*)(kc + 32);
        uint4 m10 = *(const uint4*)(kc + 1024);
        uint4 m11 = *(const uint4*)(kc + 1056);
        bfB[0][0] = *(short8*)&m00; bfB[0][1] = *(short8*)&m01;
        bfB[1][0] = *(short8*)&m10; bfB[1][1] = *(short8*)&m11;
        kc += 2048;
    }

    for (int g = 0; g < 8; ++g) {
        u16* gw = plds + (g & 1) * (4 * 528);      // this group's write buffer

        CHUNK_STEP(bfA, 0)                         // chunk 4g+0; reloads bfA for +2
        CHUNK_STEP(bfB, 1)                         // chunk 4g+1; reloads bfB for +2
        CHUNK_STEP(bfA, 2)                         // chunk 4g+2
        CHUNK_STEP(bfB, 3)                         // chunk 4g+3

        __syncthreads();

        // PV on the matrix pipe: out[q][d] += P[q][j] * (Vhi + Vlo)[d][j]
#pragma unroll
        for (int c = 0; c < 4; ++c) {
            uint4 vh = *(const uint4*)(vhp + c * 32);
            uint4 vl = *(const uint4*)(vlp + c * 32);
            short8 pf = *(const short8*)(gw + c * 528 + lane * 8);
            pvacc = __builtin_amdgcn_mfma_f32_16x16x32_bf16(pf, *(short8*)&vh, pvacc, 0, 0, 0);
            pvacc = __builtin_amdgcn_mfma_f32_16x16x32_bf16(pf, *(short8*)&vl, pvacc, 0, 0, 0);
        }
        vhp += 128;
        vlp += 128;
    }

    float l = l_run;
    l += __shfl_xor(l, 1); l += __shfl_xor(l, 2);
    l += __shfl_xor(l, 4); l += __shfl_xor(l, 8);
    if (lane == 0) l_sh[wv] = l;
    __syncthreads();

    if (hi == 0) {                                 // C rows 0..3 live on lanes 0..15
        int b = bh >> 3, h = bh & 7;
#pragma unroll
        for (int q = 0; q < 4; ++q) {
            float outv = pvacc[q] * __builtin_amdgcn_rcpf(l_sh[q]);
            ao[((b * 1024 + qbase + q) * 512) + h * 64 + wv * 16 + lo] = outv;
        }
    }
}
#undef CHUNK_STEP

// ---------------------------------------------------------------------------
extern "C" void kernel_launch(void* const* d_in, const int* in_sizes, int n_in,
                              void* d_out, int out_size, void* d_ws, size_t ws_size,
                              hipStream_t stream)
{
    (void)in_sizes; (void)n_in; (void)out_size; (void)ws_size;
    const float* x  = (const float*)d_in[0];
    const float* Wq = (const float*)d_in[1];
    const float* bq = (const float*)d_in[2];
    const float* Wk = (const float*)d_in[3];
    const float* bk = (const float*)d_in[4];
    const float* Wv = (const float*)d_in[5];
    const float* bv = (const float*)d_in[6];
    const float* w1 = (const float*)d_in[7];
    const float* b1 = (const float*)d_in[8];
    const float* w2 = (const float*)d_in[9];
    // d_in[10] = b2: scalar shift of all scores -> softmax-invariant -> unused
    const float* Wo = (const float*)d_in[11];
    const float* bo = (const float*)d_in[12];

    char* ws = (char*)d_ws;
    float* q_ws = (float*)(ws);               // 4 MB fp32 (b,h,c,d)
    u16*   k_ws = (u16*)(ws + (4u << 20));    // 2 MB bf16 (b,h,c,d)
    u16*   vthi = (u16*)(ws + (6u << 20));    // 2 MB bf16 V^T hi (b,h,d,c)
    u16*   vtlo = (u16*)(ws + (8u << 20));    // 2 MB bf16 V^T lo (b,h,d,c)
    float* a_ws = (float*)(ws + (10u << 20)); // 4 MB fp32 (b,c,D)

    dim3 blk(256);
    hipLaunchKernelGGL(gemm_qkv, dim3(32, 24), blk, 0, stream,
                       x, Wq, Wk, Wv, bq, bk, bv, q_ws, k_ws, vthi, vtlo);
    hipLaunchKernelGGL(attn22, dim3(4096), blk, 0, stream,
                       q_ws, k_ws, vthi, vtlo, w1, b1, w2, a_ws);
    hipLaunchKernelGGL(gemm_out, dim3(32, 8), blk, 0, stream, a_ws, Wo, bo, (float*)d_out);
}

// Round 11
// 452.660 us; speedup vs baseline: 1.9404x; 1.4916x over previous
//
#include <hip/hip_runtime.h>
#include <cstdint>

typedef unsigned short u16;
typedef unsigned int u32;
typedef __attribute__((ext_vector_type(8))) short short8;   // 8 bf16 (MFMA A/B frag)
typedef __attribute__((ext_vector_type(4))) float floatx4;  // MFMA C/D frag
typedef __attribute__((ext_vector_type(2))) float floatx2;  // packed f32 pair (v_pk_*_f32)

__device__ __forceinline__ float b2f(u16 u) {
    union { unsigned int i; float f; } c; c.i = ((unsigned int)u) << 16; return c.f;
}
__device__ __forceinline__ u16 f2b(float f) {
    union { float f; unsigned int i; } c; c.f = f;
    unsigned int u = c.i;
    u = u + 0x7FFFu + ((u >> 16) & 1u);   // RNE
    return (u16)(u >> 16);
}
__device__ __forceinline__ float u2f(u32 u) { union { u32 u; float f; } c; c.u = u; return c.f; }

// global -> LDS direct staging, 16B per lane, zero VGPR cost.
__device__ __forceinline__ void kstage(const u16* gsrc, u16* ldst) {
    __builtin_amdgcn_global_load_lds(
        (const __attribute__((address_space(1))) u32*)gsrc,
        (__attribute__((address_space(3))) u32*)ldst, 16, 0, 0);
}

// ---------------------------------------------------------------------------
// Fused Q/K/V projection GEMM. Y[m,n] = sum_k x[m,k]*W[n,k] + bias[n].
// grid (32, 24): which = blockIdx.y>>3 (0=q fp32, 1=k bf16, 2=v -> vt hi/lo bf16 transposed).
// ---------------------------------------------------------------------------
__global__ __launch_bounds__(256) void gemm_qkv(
    const float* __restrict__ x,
    const float* __restrict__ Wq, const float* __restrict__ Wk, const float* __restrict__ Wv,
    const float* __restrict__ bq, const float* __restrict__ bk, const float* __restrict__ bv,
    float* __restrict__ qout, u16* __restrict__ kout,
    u16* __restrict__ vthi, u16* __restrict__ vtlo)
{
    __shared__ u16 xs[64 * 72];
    __shared__ u16 wsl[64 * 72];
    int tid = threadIdx.x;
    int lane = tid & 63;
    int wv = tid >> 6;
    int lo = lane & 15, hi = lane >> 4;
    int which = blockIdx.y >> 3;
    int m0 = blockIdx.x * 64, n0 = (blockIdx.y & 7) * 64;
    const float* W    = which == 0 ? Wq : (which == 1 ? Wk : Wv);
    const float* bias = which == 0 ? bq : (which == 1 ? bk : bv);

    floatx4 acc[4];
#pragma unroll
    for (int mt = 0; mt < 4; ++mt) acc[mt] = (floatx4){0.f, 0.f, 0.f, 0.f};

    for (int k0 = 0; k0 < 512; k0 += 64) {
        __syncthreads();
#pragma unroll
        for (int i = 0; i < 2; ++i) {
            int v = tid + i * 256;
            int row = v >> 3, c8 = (v & 7) * 8;
            const float* ap = x + (m0 + row) * 512 + k0 + c8;
            const float* wp = W + (n0 + row) * 512 + k0 + c8;
            float4 a0 = *(const float4*)(ap);
            float4 a1 = *(const float4*)(ap + 4);
            float4 w0 = *(const float4*)(wp);
            float4 w1v = *(const float4*)(wp + 4);
            union { u16 u[8]; uint4 q; } ca, cw;
            ca.u[0] = f2b(a0.x); ca.u[1] = f2b(a0.y); ca.u[2] = f2b(a0.z); ca.u[3] = f2b(a0.w);
            ca.u[4] = f2b(a1.x); ca.u[5] = f2b(a1.y); ca.u[6] = f2b(a1.z); ca.u[7] = f2b(a1.w);
            cw.u[0] = f2b(w0.x); cw.u[1] = f2b(w0.y); cw.u[2] = f2b(w0.z); cw.u[3] = f2b(w0.w);
            cw.u[4] = f2b(w1v.x); cw.u[5] = f2b(w1v.y); cw.u[6] = f2b(w1v.z); cw.u[7] = f2b(w1v.w);
            *(uint4*)(xs + row * 72 + c8)  = ca.q;
            *(uint4*)(wsl + row * 72 + c8) = cw.q;
        }
        __syncthreads();
#pragma unroll
        for (int ks = 0; ks < 2; ++ks) {
            short8 bfr = *(const short8*)(wsl + (wv * 16 + lo) * 72 + ks * 32 + hi * 8);
#pragma unroll
            for (int mt = 0; mt < 4; ++mt) {
                short8 afr = *(const short8*)(xs + (mt * 16 + lo) * 72 + ks * 32 + hi * 8);
                acc[mt] = __builtin_amdgcn_mfma_f32_16x16x32_bf16(afr, bfr, acc[mt], 0, 0, 0);
            }
        }
    }

    int n = n0 + wv * 16 + lo;
    float bv2 = bias[n];
    if (which == 2) {
        // transpose V tile through LDS; emit vt_hi/vt_lo bf16 [bh][d][c]
        __syncthreads();                           // xs/wsl reuse: all waves done with MFMAs
        int nl = wv * 16 + lo;                     // local d
#pragma unroll
        for (int mt = 0; mt < 4; ++mt)
#pragma unroll
            for (int r = 0; r < 4; ++r) {
                int ml = mt * 16 + hi * 4 + r;     // local c
                float y = acc[mt][r] + bv2;
                u16 vh = f2b(y);
                u16 vl = f2b(y - b2f(vh));
                xs[nl * 72 + ml]  = vh;
                wsl[nl * 72 + ml] = vl;
            }
        __syncthreads();
        int row = tid >> 2, seg = (tid & 3) * 16;  // row = local d, seg = local c chunk
        int b = m0 >> 10, c0 = m0 & 1023, h2 = n0 >> 6;
        size_t dst = ((size_t)((b * 8 + h2) * 64 + row)) * 1024 + c0 + seg;
        *(uint4*)(vthi + dst)     = *(uint4*)(xs  + row * 72 + seg);
        *(uint4*)(vthi + dst + 8) = *(uint4*)(xs  + row * 72 + seg + 8);
        *(uint4*)(vtlo + dst)     = *(uint4*)(wsl + row * 72 + seg);
        *(uint4*)(vtlo + dst + 8) = *(uint4*)(wsl + row * 72 + seg + 8);
    } else {
        int h = n >> 6, dd = n & 63;
#pragma unroll
        for (int mt = 0; mt < 4; ++mt)
#pragma unroll
            for (int r = 0; r < 4; ++r) {
                int m = m0 + mt * 16 + hi * 4 + r;  // C/D: row=(lane>>4)*4+reg, col=lane&15
                float y = acc[mt][r] + bv2;
                int b = m >> 10, c = m & 1023;
                int idx = (((b * 8 + h) * 1024) + c) * 64 + dd;
                if (which == 0) qout[idx] = y;
                else            kout[idx] = f2b(y);
            }
    }
}

// ---------------------------------------------------------------------------
// Output GEMM: Y[m,n] = sum_k A[m,k]*Wo[n,k] + bo[n], fp32 out, [m*512+n].
// ---------------------------------------------------------------------------
__global__ __launch_bounds__(256) void gemm_out(
    const float* __restrict__ A, const float* __restrict__ W, const float* __restrict__ bias,
    float* __restrict__ outf)
{
    __shared__ u16 xs[64 * 72];
    __shared__ u16 wsl[64 * 72];
    int tid = threadIdx.x;
    int lane = tid & 63;
    int wv = tid >> 6;
    int lo = lane & 15, hi = lane >> 4;
    int m0 = blockIdx.x * 64, n0 = blockIdx.y * 64;

    floatx4 acc[4];
#pragma unroll
    for (int mt = 0; mt < 4; ++mt) acc[mt] = (floatx4){0.f, 0.f, 0.f, 0.f};

    for (int k0 = 0; k0 < 512; k0 += 64) {
        __syncthreads();
#pragma unroll
        for (int i = 0; i < 2; ++i) {
            int v = tid + i * 256;
            int row = v >> 3, c8 = (v & 7) * 8;
            const float* ap = A + (m0 + row) * 512 + k0 + c8;
            const float* wp = W + (n0 + row) * 512 + k0 + c8;
            float4 a0 = *(const float4*)(ap);
            float4 a1 = *(const float4*)(ap + 4);
            float4 w0 = *(const float4*)(wp);
            float4 w1v = *(const float4*)(wp + 4);
            union { u16 u[8]; uint4 q; } ca, cw;
            ca.u[0] = f2b(a0.x); ca.u[1] = f2b(a0.y); ca.u[2] = f2b(a0.z); ca.u[3] = f2b(a0.w);
            ca.u[4] = f2b(a1.x); ca.u[5] = f2b(a1.y); ca.u[6] = f2b(a1.z); ca.u[7] = f2b(a1.w);
            cw.u[0] = f2b(w0.x); cw.u[1] = f2b(w0.y); cw.u[2] = f2b(w0.z); cw.u[3] = f2b(w0.w);
            cw.u[4] = f2b(w1v.x); cw.u[5] = f2b(w1v.y); cw.u[6] = f2b(w1v.z); cw.u[7] = f2b(w1v.w);
            *(uint4*)(xs + row * 72 + c8)  = ca.q;
            *(uint4*)(wsl + row * 72 + c8) = cw.q;
        }
        __syncthreads();
#pragma unroll
        for (int ks = 0; ks < 2; ++ks) {
            short8 bfr = *(const short8*)(wsl + (wv * 16 + lo) * 72 + ks * 32 + hi * 8);
#pragma unroll
            for (int mt = 0; mt < 4; ++mt) {
                short8 afr = *(const short8*)(xs + (mt * 16 + lo) * 72 + ks * 32 + hi * 8);
                acc[mt] = __builtin_amdgcn_mfma_f32_16x16x32_bf16(afr, bfr, acc[mt], 0, 0, 0);
            }
        }
    }

    int n = n0 + wv * 16 + lo;
    float bv = bias[n];
#pragma unroll
    for (int mt = 0; mt < 4; ++mt)
#pragma unroll
        for (int r = 0; r < 4; ++r) {
            int m = m0 + mt * 16 + hi * 4 + r;
            outf[m * 512 + n] = acc[mt][r] + bv;
        }
}

// ---------------------------------------------------------------------------
// Fused second-order attention, v23 = v18 (best no-spill structure, 497 us)
// with K staging moved to LDS via global_load_lds -- the only prefetch that
// costs ZERO arch VGPRs (v19-v22 post-mortems: at (256,4) the allocator
// hard-partitions 64 arch + 64 acc; every register-funded prefetch spilled):
//  - kbuf[2][4KB] LDS ring; per chunk, each of the 4 waves issues ONE
//    global_load_lds (16B/lane = 1KB) for chunk c+1 -> 4KB staged, and the
//    4x redundant per-wave K loads of v18 are gone.
//  - per-chunk __syncthreads (33 total; v17 proved barrier count is free).
//    The compiler's vmcnt(0)-before-barrier drain IS the completion
//    guarantee: stage issued at top of chunk c, drained at top of c+1 ->
//    a full chunk (~600 cyc) of cover > L2 latency. Chunk-top cost drops
//    to a ~120cyc ds_read_b128, overlapped by PV/prologue.
//  - bf stays 16 regs; scoring/qpinit/wcp byte-identical to v18.
//  - PV for group g runs right after group g+1's first barrier (plds
//    double-buffer safety preserved: writes to plds[g&1] resume only in
//    group g+2, behind barriers all readers have passed).
// ---------------------------------------------------------------------------
#define CHUNK_LOAD(BUFI)                                                       \
    {                                                                          \
        const u16* kl = kbuf + (BUFI) * 2048;                                  \
        bf[0][0] = *(const short8*)(kl + lo * 64 + hi * 8);                    \
        bf[0][1] = *(const short8*)(kl + lo * 64 + 32 + hi * 8);               \
        bf[1][0] = *(const short8*)(kl + (lo + 16) * 64 + hi * 8);             \
        bf[1][1] = *(const short8*)(kl + (lo + 16) * 64 + 32 + hi * 8);        \
        kstage(kg, kbuf + ((BUFI) ^ 1) * 2048 + wv * 512);                     \
        kg += 2048;                                                            \
    }

#define CHUNK_SCORE(CIDX)                                                      \
    {                                                                          \
        floatx2 s0v = (floatx2){0.f, 0.f};                                     \
        floatx2 s1v = (floatx2){0.f, 0.f};                                     \
        floatx4 aP[2], aN[2];                                                  \
        aP[0] = __builtin_amdgcn_mfma_f32_16x16x32_bf16(af[0][0], bf[0][0], qpinit[0], 0, 0, 0); \
        aP[0] = __builtin_amdgcn_mfma_f32_16x16x32_bf16(af[0][1], bf[0][1], aP[0], 0, 0, 0); \
        aP[1] = __builtin_amdgcn_mfma_f32_16x16x32_bf16(af[0][0], bf[1][0], qpinit[0], 0, 0, 0); \
        aP[1] = __builtin_amdgcn_mfma_f32_16x16x32_bf16(af[0][1], bf[1][1], aP[1], 0, 0, 0); \
        _Pragma("unroll")                                                      \
        for (int mt = 0; mt < 4; ++mt) {                                       \
            if (mt < 3) {                                                      \
                aN[0] = __builtin_amdgcn_mfma_f32_16x16x32_bf16(af[mt + 1][0], bf[0][0], qpinit[mt + 1], 0, 0, 0); \
                aN[0] = __builtin_amdgcn_mfma_f32_16x16x32_bf16(af[mt + 1][1], bf[0][1], aN[0], 0, 0, 0); \
                aN[1] = __builtin_amdgcn_mfma_f32_16x16x32_bf16(af[mt + 1][0], bf[1][0], qpinit[mt + 1], 0, 0, 0); \
                aN[1] = __builtin_amdgcn_mfma_f32_16x16x32_bf16(af[mt + 1][1], bf[1][1], aN[1], 0, 0, 0); \
            }                                                                  \
            _Pragma("unroll")                                                  \
            for (int h2 = 0; h2 < 2; ++h2) {                                   \
                u32 wp = wcp[mt][h2];                                          \
                floatx2 wv2 = (floatx2){u2f(wp << 16), u2f(wp & 0xFFFF0000u)}; \
                _Pragma("unroll")                                              \
                for (int t = 0; t < 2; ++t) {                                  \
                    floatx2 x = (floatx2){aP[t][h2 * 2 + 0], aP[t][h2 * 2 + 1]}; \
                    floatx2 ex = (floatx2){__builtin_amdgcn_exp2f(x.x),        \
                                           __builtin_amdgcn_exp2f(x.y)};       \
                    floatx2 a = ex + 1.0f;                                     \
                    float rc = __builtin_amdgcn_rcpf(a.x * a.y);               \
                    floatx2 sw = (floatx2){a.y, a.x};                          \
                    floatx2 contrib = (x * wv2) * (sw * rc);                   \
                    if (t == 0) s0v += contrib; else s1v += contrib;           \
                }                                                              \
            }                                                                  \
            aP[0] = aN[0];                                                     \
            aP[1] = aN[1];                                                     \
        }                                                                      \
        float s0 = s0v.x + s0v.y, s1 = s1v.x + s1v.y;                          \
        s0 += __shfl_xor(s0, 16); s0 += __shfl_xor(s0, 32);                    \
        s1 += __shfl_xor(s1, 16); s1 += __shfl_xor(s1, 32);                    \
        float p0 = __builtin_amdgcn_exp2f(s0 - 16.0f);                         \
        float p1 = __builtin_amdgcn_exp2f(s1 - 16.0f);                         \
        u16 ph0 = f2b(p0);                                                     \
        u16 ph1 = f2b(p1);                                                     \
        l_run += b2f(ph0) + b2f(ph1);                                          \
        u16* pw = gw + (CIDX) * 528;                                           \
        if (lane < 16) {                                                       \
            pw[((lo >> 3) * 16 + wv) * 8 + (lo & 7)] = ph0;                    \
            pw[((2 + (lo >> 3)) * 16 + wv) * 8 + (lo & 7)] = ph1;              \
        }                                                                      \
    }

#define PV_GROUP(PGW)                                                          \
    {                                                                          \
        _Pragma("unroll")                                                      \
        for (int c2 = 0; c2 < 4; ++c2) {                                       \
            uint4 vh = *(const uint4*)(vhp + c2 * 32);                         \
            uint4 vl = *(const uint4*)(vlp + c2 * 32);                         \
            short8 pf = *(const short8*)((PGW) + c2 * 528 + lane * 8);         \
            pvacc = __builtin_amdgcn_mfma_f32_16x16x32_bf16(pf, *(short8*)&vh, pvacc, 0, 0, 0); \
            pvacc = __builtin_amdgcn_mfma_f32_16x16x32_bf16(pf, *(short8*)&vl, pvacc, 0, 0, 0); \
        }                                                                      \
        vhp += 128;                                                            \
        vlp += 128;                                                            \
    }

__global__ __launch_bounds__(256, 4) void attn23(
    const float* __restrict__ qf, const u16* __restrict__ kb,
    const u16* __restrict__ vthi, const u16* __restrict__ vtlo,
    const float* __restrict__ w1, const float* __restrict__ b1, const float* __restrict__ w2,
    float* __restrict__ ao)
{
    __shared__ float q_l[4 * 64];
    __shared__ __align__(16) u16 plds[2 * 4 * 528];   // [dbuf][chunk plane 528][A-frag order]
    __shared__ __align__(16) u16 kbuf[2 * 2048];      // 2 x 4KB K-chunk ring
    __shared__ float l_sh[4];
    int tid = threadIdx.x;
    int lane = tid & 63;
    int wv = tid >> 6;
    int lo = lane & 15, hi = lane >> 4;
    int bh = blockIdx.x >> 8;                      // 0..15 = b*8+h
    int qbase = (blockIdx.x & 255) << 2;           // block's first query
    int qi = qbase | wv;                           // this wave's query

    const float NA = -2.45546696f;                 // -1.702 * log2(e)

    // zero p-LDS once: A-frag rows q=4..15 must stay 0 so PV C rows 4..15 are clean
    for (int i = tid; i < 2112; i += 256) ((u32*)plds)[i] = 0;

    q_l[wv * 64 + lane] = qf[(bh * 1024 + qi) * 64 + lane];

    // qp[e]+b1[e] at lane=e
    float qpacc = b1[lane];
#pragma unroll
    for (int d8 = 0; d8 < 64; d8 += 8) {
        float4 wa = *(const float4*)(w1 + lane * 192 + d8);
        float4 wb = *(const float4*)(w1 + lane * 192 + d8 + 4);
        const float* q8 = q_l + wv * 64 + d8;      // wave-uniform broadcast reads
        qpacc = __builtin_fmaf(q8[0], wa.x, qpacc);
        qpacc = __builtin_fmaf(q8[1], wa.y, qpacc);
        qpacc = __builtin_fmaf(q8[2], wa.z, qpacc);
        qpacc = __builtin_fmaf(q8[3], wa.w, qpacc);
        qpacc = __builtin_fmaf(q8[4], wb.x, qpacc);
        qpacc = __builtin_fmaf(q8[5], wb.y, qpacc);
        qpacc = __builtin_fmaf(q8[6], wb.z, qpacc);
        qpacc = __builtin_fmaf(q8[7], wb.w, qpacc);
    }
    qpacc *= NA;                                   // qp' = c * (qp + b1)

    // w2c packed: wc' = w2[e] * (1/8)*log2e / c = w2[e] * -0.07344288
    u32 wcp[4][2];
    float w2row = w2[lane] * -0.07344288f;
#pragma unroll
    for (int mt = 0; mt < 4; ++mt)
#pragma unroll
        for (int h2 = 0; h2 < 2; ++h2) {
            int e0 = mt * 16 + hi * 4 + h2 * 2;
            u32 lo16 = (u32)f2b(__shfl(w2row, e0));
            u32 hi16 = (u32)f2b(__shfl(w2row, e0 + 1));
            wcp[mt][h2] = (hi16 << 16) | lo16;
        }

    // q pieces for frag build: qv2[ks][j] = q[ks*32 + hi*8 + j]
    float qv2[2][8];
#pragma unroll
    for (int ks = 0; ks < 2; ++ks)
#pragma unroll
        for (int j = 0; j < 8; ++j)
            qv2[ks][j] = q_l[wv * 64 + ks * 32 + hi * 8 + j];

    // A-frags: c * qw'[e = mt*16+lo][dd = ks*32 + hi*8 + j], bf16
    short8 af[4][2];
#pragma unroll
    for (int mt = 0; mt < 4; ++mt) {
        const float* wr = w1 + (mt * 16 + lo) * 192;
#pragma unroll
        for (int ks = 0; ks < 2; ++ks) {
            int dd0 = ks * 32 + hi * 8;
            float4 a0 = *(const float4*)(wr + 128 + dd0);
            float4 a1 = *(const float4*)(wr + 128 + dd0 + 4);
            float4 k0 = *(const float4*)(wr + 64 + dd0);
            float4 k1 = *(const float4*)(wr + 64 + dd0 + 4);
            union { u16 u[8]; short8 s; } cv;
            cv.u[0] = f2b(NA * __builtin_fmaf(qv2[ks][0], a0.x, k0.x));
            cv.u[1] = f2b(NA * __builtin_fmaf(qv2[ks][1], a0.y, k0.y));
            cv.u[2] = f2b(NA * __builtin_fmaf(qv2[ks][2], a0.z, k0.z));
            cv.u[3] = f2b(NA * __builtin_fmaf(qv2[ks][3], a0.w, k0.w));
            cv.u[4] = f2b(NA * __builtin_fmaf(qv2[ks][4], a1.x, k1.x));
            cv.u[5] = f2b(NA * __builtin_fmaf(qv2[ks][5], a1.y, k1.y));
            cv.u[6] = f2b(NA * __builtin_fmaf(qv2[ks][6], a1.z, k1.z));
            cv.u[7] = f2b(NA * __builtin_fmaf(qv2[ks][7], a1.w, k1.w));
            af[mt][ks] = cv.s;
        }
    }

    // rank-1 qp' C-init, loop-invariant (v18-verified)
    floatx4 qpinit[4];
    {
        const floatx4 z = (floatx4){0.f, 0.f, 0.f, 0.f};
        union { u16 u[8]; short8 s; } bb;
#pragma unroll
        for (int i = 0; i < 8; ++i) bb.u[i] = 0;
        bb.u[0] = (hi == 0) ? (u16)0x3F80 : (u16)0;   // bf16 1.0 at k=0
#pragma unroll
        for (int mt = 0; mt < 4; ++mt) {
            float qpv = __shfl(qpacc, mt * 16 + lo);
            union { u16 u[8]; short8 s; } aa;
#pragma unroll
            for (int i = 0; i < 8; ++i) aa.u[i] = 0;
            aa.u[0] = (hi == 0) ? f2b(qpv) : (u16)0;
            qpinit[mt] = __builtin_amdgcn_mfma_f32_16x16x32_bf16(aa.s, bb.s, z, 0, 0, 0);
        }
    }

    // per-lane walking K source + chunk-0 stage (each wave 1KB)
    const u16* kg = kb + bh * 65536 + wv * 512 + lane * 8;
    kstage(kg, kbuf + wv * 512);
    kg += 2048;

    // drains chunk-0 staging (vmcnt) + plds zero-init + q_l, block-wide
    __syncthreads();

    float l_run = 0.f;
    floatx4 pvacc = (floatx4){0.f, 0.f, 0.f, 0.f};   // out[q=row 0..3][d = wv*16+col]
    // V^T B-frag bases: this wave's d-tile row = wv*16+lo, k-offset hi*8
    const u16* vhp = vthi + bh * 65536 + (wv * 16 + lo) * 1024 + hi * 8;
    const u16* vlp = vtlo + bh * 65536 + (wv * 16 + lo) * 1024 + hi * 8;
    short8 bf[2][2];

    for (int g = 0; g < 8; ++g) {
        u16* gw  = plds + (g & 1) * (4 * 528);         // this group's write buffer
        u16* pgw = plds + ((g & 1) ^ 1) * (4 * 528);   // previous group's buffer

        // chunk 4g+0 (kbuf parity 0)
        CHUNK_LOAD(0)
        if (g > 0) { PV_GROUP(pgw) }                   // PV for group g-1
        CHUNK_SCORE(0)
        __syncthreads();
        // chunk 4g+1
        CHUNK_LOAD(1)
        CHUNK_SCORE(1)
        __syncthreads();
        // chunk 4g+2
        CHUNK_LOAD(0)
        CHUNK_SCORE(2)
        __syncthreads();
        // chunk 4g+3
        CHUNK_LOAD(1)
        CHUNK_SCORE(3)
        __syncthreads();
    }

    // trailing PV for group 7 (plds[1]); publishes drained by the loop's last barrier
    PV_GROUP(plds + (4 * 528))

    float l = l_run;
    l += __shfl_xor(l, 1); l += __shfl_xor(l, 2);
    l += __shfl_xor(l, 4); l += __shfl_xor(l, 8);
    if (lane == 0) l_sh[wv] = l;
    __syncthreads();

    if (hi == 0) {                                 // C rows 0..3 live on lanes 0..15
        int b = bh >> 3, h = bh & 7;
#pragma unroll
        for (int q = 0; q < 4; ++q) {
            float outv = pvacc[q] * __builtin_amdgcn_rcpf(l_sh[q]);
            ao[((b * 1024 + qbase + q) * 512) + h * 64 + wv * 16 + lo] = outv;
        }
    }
}
#undef CHUNK_LOAD
#undef CHUNK_SCORE
#undef PV_GROUP

// ---------------------------------------------------------------------------
extern "C" void kernel_launch(void* const* d_in, const int* in_sizes, int n_in,
                              void* d_out, int out_size, void* d_ws, size_t ws_size,
                              hipStream_t stream)
{
    (void)in_sizes; (void)n_in; (void)out_size; (void)ws_size;
    const float* x  = (const float*)d_in[0];
    const float* Wq = (const float*)d_in[1];
    const float* bq = (const float*)d_in[2];
    const float* Wk = (const float*)d_in[3];
    const float* bk = (const float*)d_in[4];
    const float* Wv = (const float*)d_in[5];
    const float* bv = (const float*)d_in[6];
    const float* w1 = (const float*)d_in[7];
    const float* b1 = (const float*)d_in[8];
    const float* w2 = (const float*)d_in[9];
    // d_in[10] = b2: scalar shift of all scores -> softmax-invariant -> unused
    const float* Wo = (const float*)d_in[11];
    const float* bo = (const float*)d_in[12];

    char* ws = (char*)d_ws;
    float* q_ws = (float*)(ws);               // 4 MB fp32 (b,h,c,d)
    u16*   k_ws = (u16*)(ws + (4u << 20));    // 2 MB bf16 (b,h,c,d)
    u16*   vthi = (u16*)(ws + (6u << 20));    // 2 MB bf16 V^T hi (b,h,d,c)
    u16*   vtlo = (u16*)(ws + (8u << 20));    // 2 MB bf16 V^T lo (b,h,d,c)
    float* a_ws = (float*)(ws + (10u << 20)); // 4 MB fp32 (b,c,D)

    dim3 blk(256);
    hipLaunchKernelGGL(gemm_qkv, dim3(32, 24), blk, 0, stream,
                       x, Wq, Wk, Wv, bq, bk, bv, q_ws, k_ws, vthi, vtlo);
    hipLaunchKernelGGL(attn23, dim3(4096), blk, 0, stream,
                       q_ws, k_ws, vthi, vtlo, w1, b1, w2, a_ws);
    hipLaunchKernelGGL(gemm_out, dim3(32, 8), blk, 0, stream, a_ws, Wo, bo, (float*)d_out);
}

// Round 12
// 449.134 us; speedup vs baseline: 1.9556x; 1.0079x over previous
//
#include <hip/hip_runtime.h>
#include <cstdint>

typedef unsigned short u16;
typedef unsigned int u32;
typedef __attribute__((ext_vector_type(8))) short short8;   // 8 bf16 (MFMA A/B frag)
typedef __attribute__((ext_vector_type(4))) float floatx4;  // MFMA C/D frag
typedef __attribute__((ext_vector_type(2))) float floatx2;  // packed f32 pair (v_pk_*_f32)

__device__ __forceinline__ float b2f(u16 u) {
    union { unsigned int i; float f; } c; c.i = ((unsigned int)u) << 16; return c.f;
}
__device__ __forceinline__ u16 f2b(float f) {
    union { float f; unsigned int i; } c; c.f = f;
    unsigned int u = c.i;
    u = u + 0x7FFFu + ((u >> 16) & 1u);   // RNE
    return (u16)(u >> 16);
}
__device__ __forceinline__ float u2f(u32 u) { union { u32 u; float f; } c; c.u = u; return c.f; }

// global -> LDS direct staging, 16B per lane, zero VGPR cost.
__device__ __forceinline__ void kstage(const u16* gsrc, u16* ldst) {
    __builtin_amdgcn_global_load_lds(
        (const __attribute__((address_space(1))) u32*)gsrc,
        (__attribute__((address_space(3))) u32*)ldst, 16, 0, 0);
}

// ---------------------------------------------------------------------------
// Fused Q/K/V projection GEMM. Y[m,n] = sum_k x[m,k]*W[n,k] + bias[n].
// grid (32, 24): which = blockIdx.y>>3 (0=q fp32, 1=k bf16, 2=v -> vt hi/lo bf16 transposed).
// ---------------------------------------------------------------------------
__global__ __launch_bounds__(256) void gemm_qkv(
    const float* __restrict__ x,
    const float* __restrict__ Wq, const float* __restrict__ Wk, const float* __restrict__ Wv,
    const float* __restrict__ bq, const float* __restrict__ bk, const float* __restrict__ bv,
    float* __restrict__ qout, u16* __restrict__ kout,
    u16* __restrict__ vthi, u16* __restrict__ vtlo)
{
    __shared__ u16 xs[64 * 72];
    __shared__ u16 wsl[64 * 72];
    int tid = threadIdx.x;
    int lane = tid & 63;
    int wv = tid >> 6;
    int lo = lane & 15, hi = lane >> 4;
    int which = blockIdx.y >> 3;
    int m0 = blockIdx.x * 64, n0 = (blockIdx.y & 7) * 64;
    const float* W    = which == 0 ? Wq : (which == 1 ? Wk : Wv);
    const float* bias = which == 0 ? bq : (which == 1 ? bk : bv);

    floatx4 acc[4];
#pragma unroll
    for (int mt = 0; mt < 4; ++mt) acc[mt] = (floatx4){0.f, 0.f, 0.f, 0.f};

    for (int k0 = 0; k0 < 512; k0 += 64) {
        __syncthreads();
#pragma unroll
        for (int i = 0; i < 2; ++i) {
            int v = tid + i * 256;
            int row = v >> 3, c8 = (v & 7) * 8;
            const float* ap = x + (m0 + row) * 512 + k0 + c8;
            const float* wp = W + (n0 + row) * 512 + k0 + c8;
            float4 a0 = *(const float4*)(ap);
            float4 a1 = *(const float4*)(ap + 4);
            float4 w0 = *(const float4*)(wp);
            float4 w1v = *(const float4*)(wp + 4);
            union { u16 u[8]; uint4 q; } ca, cw;
            ca.u[0] = f2b(a0.x); ca.u[1] = f2b(a0.y); ca.u[2] = f2b(a0.z); ca.u[3] = f2b(a0.w);
            ca.u[4] = f2b(a1.x); ca.u[5] = f2b(a1.y); ca.u[6] = f2b(a1.z); ca.u[7] = f2b(a1.w);
            cw.u[0] = f2b(w0.x); cw.u[1] = f2b(w0.y); cw.u[2] = f2b(w0.z); cw.u[3] = f2b(w0.w);
            cw.u[4] = f2b(w1v.x); cw.u[5] = f2b(w1v.y); cw.u[6] = f2b(w1v.z); cw.u[7] = f2b(w1v.w);
            *(uint4*)(xs + row * 72 + c8)  = ca.q;
            *(uint4*)(wsl + row * 72 + c8) = cw.q;
        }
        __syncthreads();
#pragma unroll
        for (int ks = 0; ks < 2; ++ks) {
            short8 bfr = *(const short8*)(wsl + (wv * 16 + lo) * 72 + ks * 32 + hi * 8);
#pragma unroll
            for (int mt = 0; mt < 4; ++mt) {
                short8 afr = *(const short8*)(xs + (mt * 16 + lo) * 72 + ks * 32 + hi * 8);
                acc[mt] = __builtin_amdgcn_mfma_f32_16x16x32_bf16(afr, bfr, acc[mt], 0, 0, 0);
            }
        }
    }

    int n = n0 + wv * 16 + lo;
    float bv2 = bias[n];
    if (which == 2) {
        // transpose V tile through LDS; emit vt_hi/vt_lo bf16 [bh][d][c]
        __syncthreads();                           // xs/wsl reuse: all waves done with MFMAs
        int nl = wv * 16 + lo;                     // local d
#pragma unroll
        for (int mt = 0; mt < 4; ++mt)
#pragma unroll
            for (int r = 0; r < 4; ++r) {
                int ml = mt * 16 + hi * 4 + r;     // local c
                float y = acc[mt][r] + bv2;
                u16 vh = f2b(y);
                u16 vl = f2b(y - b2f(vh));
                xs[nl * 72 + ml]  = vh;
                wsl[nl * 72 + ml] = vl;
            }
        __syncthreads();
        int row = tid >> 2, seg = (tid & 3) * 16;  // row = local d, seg = local c chunk
        int b = m0 >> 10, c0 = m0 & 1023, h2 = n0 >> 6;
        size_t dst = ((size_t)((b * 8 + h2) * 64 + row)) * 1024 + c0 + seg;
        *(uint4*)(vthi + dst)     = *(uint4*)(xs  + row * 72 + seg);
        *(uint4*)(vthi + dst + 8) = *(uint4*)(xs  + row * 72 + seg + 8);
        *(uint4*)(vtlo + dst)     = *(uint4*)(wsl + row * 72 + seg);
        *(uint4*)(vtlo + dst + 8) = *(uint4*)(wsl + row * 72 + seg + 8);
    } else {
        int h = n >> 6, dd = n & 63;
#pragma unroll
        for (int mt = 0; mt < 4; ++mt)
#pragma unroll
            for (int r = 0; r < 4; ++r) {
                int m = m0 + mt * 16 + hi * 4 + r;  // C/D: row=(lane>>4)*4+reg, col=lane&15
                float y = acc[mt][r] + bv2;
                int b = m >> 10, c = m & 1023;
                int idx = (((b * 8 + h) * 1024) + c) * 64 + dd;
                if (which == 0) qout[idx] = y;
                else            kout[idx] = f2b(y);
            }
    }
}

// ---------------------------------------------------------------------------
// Output GEMM: Y[m,n] = sum_k A[m,k]*Wo[n,k] + bo[n], fp32 out, [m*512+n].
// ---------------------------------------------------------------------------
__global__ __launch_bounds__(256) void gemm_out(
    const float* __restrict__ A, const float* __restrict__ W, const float* __restrict__ bias,
    float* __restrict__ outf)
{
    __shared__ u16 xs[64 * 72];
    __shared__ u16 wsl[64 * 72];
    int tid = threadIdx.x;
    int lane = tid & 63;
    int wv = tid >> 6;
    int lo = lane & 15, hi = lane >> 4;
    int m0 = blockIdx.x * 64, n0 = blockIdx.y * 64;

    floatx4 acc[4];
#pragma unroll
    for (int mt = 0; mt < 4; ++mt) acc[mt] = (floatx4){0.f, 0.f, 0.f, 0.f};

    for (int k0 = 0; k0 < 512; k0 += 64) {
        __syncthreads();
#pragma unroll
        for (int i = 0; i < 2; ++i) {
            int v = tid + i * 256;
            int row = v >> 3, c8 = (v & 7) * 8;
            const float* ap = A + (m0 + row) * 512 + k0 + c8;
            const float* wp = W + (n0 + row) * 512 + k0 + c8;
            float4 a0 = *(const float4*)(ap);
            float4 a1 = *(const float4*)(ap + 4);
            float4 w0 = *(const float4*)(wp);
            float4 w1v = *(const float4*)(wp + 4);
            union { u16 u[8]; uint4 q; } ca, cw;
            ca.u[0] = f2b(a0.x); ca.u[1] = f2b(a0.y); ca.u[2] = f2b(a0.z); ca.u[3] = f2b(a0.w);
            ca.u[4] = f2b(a1.x); ca.u[5] = f2b(a1.y); ca.u[6] = f2b(a1.z); ca.u[7] = f2b(a1.w);
            cw.u[0] = f2b(w0.x); cw.u[1] = f2b(w0.y); cw.u[2] = f2b(w0.z); cw.u[3] = f2b(w0.w);
            cw.u[4] = f2b(w1v.x); cw.u[5] = f2b(w1v.y); cw.u[6] = f2b(w1v.z); cw.u[7] = f2b(w1v.w);
            *(uint4*)(xs + row * 72 + c8)  = ca.q;
            *(uint4*)(wsl + row * 72 + c8) = cw.q;
        }
        __syncthreads();
#pragma unroll
        for (int ks = 0; ks < 2; ++ks) {
            short8 bfr = *(const short8*)(wsl + (wv * 16 + lo) * 72 + ks * 32 + hi * 8);
#pragma unroll
            for (int mt = 0; mt < 4; ++mt) {
                short8 afr = *(const short8*)(xs + (mt * 16 + lo) * 72 + ks * 32 + hi * 8);
                acc[mt] = __builtin_amdgcn_mfma_f32_16x16x32_bf16(afr, bfr, acc[mt], 0, 0, 0);
            }
        }
    }

    int n = n0 + wv * 16 + lo;
    float bv = bias[n];
#pragma unroll
    for (int mt = 0; mt < 4; ++mt)
#pragma unroll
        for (int r = 0; r < 4; ++r) {
            int m = m0 + mt * 16 + hi * 4 + r;
            outf[m * 512 + n] = acc[mt][r] + bv;
        }
}

// ---------------------------------------------------------------------------
// Fused second-order attention, v24 = v23 (LDS-staged K via global_load_lds,
// 405 us) + BOTH-SIDES K XOR-SWIZZLE to kill the 16-way ds_read_b128 bank
// conflict the v23 PMC exposed (SQ_LDS_BANK_CONFLICT 1e6 -> 2.6e7):
//  - LDS K chunk is [32 rows][8 x 16B cols]; row stride 128B = 32 banks, so
//    bank depends only on col -> v23's reads used 4 of 8 col groups (16-way).
//  - Swizzle col' = col ^ (row&7). global_load_lds writes linearly, so the
//    permutation is applied on the GLOBAL source address per lane (each lane
//    loads the 16B unit its LDS slot must hold) and on the READ address
//    (ksw = hi ^ (lo&7); cols ksw and ksw^4; rows lo/lo+16 share lo&7).
//    ksw is perfectly balanced (each of 8 values x8 lanes) -> b128 floor.
//  - vlp walking pointer dropped (vtlo = vthi + 1M u16, derived per group):
//    -2 arch regs toward the 64-reg boundary (v23 showed ~47MB spill).
// Math byte-identical to v23 (passed, absmax 7.3e-4).
// ---------------------------------------------------------------------------
#define CHUNK_LOAD(BUFI)                                                       \
    {                                                                          \
        bf[0][0] = *(const short8*)(kr0 + (BUFI) * 2048);                      \
        bf[0][1] = *(const short8*)(kr1 + (BUFI) * 2048);                      \
        bf[1][0] = *(const short8*)(kr0 + (BUFI) * 2048 + 1024);               \
        bf[1][1] = *(const short8*)(kr1 + (BUFI) * 2048 + 1024);               \
        kstage(kg, kstg + (((BUFI) ^ 1) * 2048));                              \
        kg += 2048;                                                            \
    }

#define CHUNK_SCORE(CIDX)                                                      \
    {                                                                          \
        floatx2 s0v = (floatx2){0.f, 0.f};                                     \
        floatx2 s1v = (floatx2){0.f, 0.f};                                     \
        floatx4 aP[2], aN[2];                                                  \
        aP[0] = __builtin_amdgcn_mfma_f32_16x16x32_bf16(af[0][0], bf[0][0], qpinit[0], 0, 0, 0); \
        aP[0] = __builtin_amdgcn_mfma_f32_16x16x32_bf16(af[0][1], bf[0][1], aP[0], 0, 0, 0); \
        aP[1] = __builtin_amdgcn_mfma_f32_16x16x32_bf16(af[0][0], bf[1][0], qpinit[0], 0, 0, 0); \
        aP[1] = __builtin_amdgcn_mfma_f32_16x16x32_bf16(af[0][1], bf[1][1], aP[1], 0, 0, 0); \
        _Pragma("unroll")                                                      \
        for (int mt = 0; mt < 4; ++mt) {                                       \
            if (mt < 3) {                                                      \
                aN[0] = __builtin_amdgcn_mfma_f32_16x16x32_bf16(af[mt + 1][0], bf[0][0], qpinit[mt + 1], 0, 0, 0); \
                aN[0] = __builtin_amdgcn_mfma_f32_16x16x32_bf16(af[mt + 1][1], bf[0][1], aN[0], 0, 0, 0); \
                aN[1] = __builtin_amdgcn_mfma_f32_16x16x32_bf16(af[mt + 1][0], bf[1][0], qpinit[mt + 1], 0, 0, 0); \
                aN[1] = __builtin_amdgcn_mfma_f32_16x16x32_bf16(af[mt + 1][1], bf[1][1], aN[1], 0, 0, 0); \
            }                                                                  \
            _Pragma("unroll")                                                  \
            for (int h2 = 0; h2 < 2; ++h2) {                                   \
                u32 wp = wcp[mt][h2];                                          \
                floatx2 wv2 = (floatx2){u2f(wp << 16), u2f(wp & 0xFFFF0000u)}; \
                _Pragma("unroll")                                              \
                for (int t = 0; t < 2; ++t) {                                  \
                    floatx2 x = (floatx2){aP[t][h2 * 2 + 0], aP[t][h2 * 2 + 1]}; \
                    floatx2 ex = (floatx2){__builtin_amdgcn_exp2f(x.x),        \
                                           __builtin_amdgcn_exp2f(x.y)};       \
                    floatx2 a = ex + 1.0f;                                     \
                    float rc = __builtin_amdgcn_rcpf(a.x * a.y);               \
                    floatx2 sw = (floatx2){a.y, a.x};                          \
                    floatx2 contrib = (x * wv2) * (sw * rc);                   \
                    if (t == 0) s0v += contrib; else s1v += contrib;           \
                }                                                              \
            }                                                                  \
            aP[0] = aN[0];                                                     \
            aP[1] = aN[1];                                                     \
        }                                                                      \
        float s0 = s0v.x + s0v.y, s1 = s1v.x + s1v.y;                          \
        s0 += __shfl_xor(s0, 16); s0 += __shfl_xor(s0, 32);                    \
        s1 += __shfl_xor(s1, 16); s1 += __shfl_xor(s1, 32);                    \
        float p0 = __builtin_amdgcn_exp2f(s0 - 16.0f);                         \
        float p1 = __builtin_amdgcn_exp2f(s1 - 16.0f);                         \
        u16 ph0 = f2b(p0);                                                     \
        u16 ph1 = f2b(p1);                                                     \
        l_run += b2f(ph0) + b2f(ph1);                                          \
        u16* pw = gw + (CIDX) * 528;                                           \
        if (lane < 16) {                                                       \
            pw[((lo >> 3) * 16 + wv) * 8 + (lo & 7)] = ph0;                    \
            pw[((2 + (lo >> 3)) * 16 + wv) * 8 + (lo & 7)] = ph1;              \
        }                                                                      \
    }

#define PV_GROUP(PGW)                                                          \
    {                                                                          \
        const u16* vlp = vhp + (1u << 20);         /* vtlo = vthi + 2MB */     \
        _Pragma("unroll")                                                      \
        for (int c2 = 0; c2 < 4; ++c2) {                                       \
            uint4 vh = *(const uint4*)(vhp + c2 * 32);                         \
            uint4 vl = *(const uint4*)(vlp + c2 * 32);                         \
            short8 pf = *(const short8*)((PGW) + c2 * 528 + lane * 8);         \
            pvacc = __builtin_amdgcn_mfma_f32_16x16x32_bf16(pf, *(short8*)&vh, pvacc, 0, 0, 0); \
            pvacc = __builtin_amdgcn_mfma_f32_16x16x32_bf16(pf, *(short8*)&vl, pvacc, 0, 0, 0); \
        }                                                                      \
        vhp += 128;                                                            \
    }

__global__ __launch_bounds__(256, 4) void attn24(
    const float* __restrict__ qf, const u16* __restrict__ kb,
    const u16* __restrict__ vthi, const u16* __restrict__ vtlo,
    const float* __restrict__ w1, const float* __restrict__ b1, const float* __restrict__ w2,
    float* __restrict__ ao)
{
    __shared__ float q_l[4 * 64];
    __shared__ __align__(16) u16 plds[2 * 4 * 528];   // [dbuf][chunk plane 528][A-frag order]
    __shared__ __align__(16) u16 kbuf[2 * 2048];      // 2 x 4KB K-chunk ring (col-swizzled)
    __shared__ float l_sh[4];
    int tid = threadIdx.x;
    int lane = tid & 63;
    int wv = tid >> 6;
    int lo = lane & 15, hi = lane >> 4;
    int bh = blockIdx.x >> 8;                      // 0..15 = b*8+h
    int qbase = (blockIdx.x & 255) << 2;           // block's first query
    int qi = qbase | wv;                           // this wave's query

    const float NA = -2.45546696f;                 // -1.702 * log2(e)

    // zero p-LDS once: A-frag rows q=4..15 must stay 0 so PV C rows 4..15 are clean
    for (int i = tid; i < 2112; i += 256) ((u32*)plds)[i] = 0;

    q_l[wv * 64 + lane] = qf[(bh * 1024 + qi) * 64 + lane];

    // qp[e]+b1[e] at lane=e
    float qpacc = b1[lane];
#pragma unroll
    for (int d8 = 0; d8 < 64; d8 += 8) {
        float4 wa = *(const float4*)(w1 + lane * 192 + d8);
        float4 wb = *(const float4*)(w1 + lane * 192 + d8 + 4);
        const float* q8 = q_l + wv * 64 + d8;      // wave-uniform broadcast reads
        qpacc = __builtin_fmaf(q8[0], wa.x, qpacc);
        qpacc = __builtin_fmaf(q8[1], wa.y, qpacc);
        qpacc = __builtin_fmaf(q8[2], wa.z, qpacc);
        qpacc = __builtin_fmaf(q8[3], wa.w, qpacc);
        qpacc = __builtin_fmaf(q8[4], wb.x, qpacc);
        qpacc = __builtin_fmaf(q8[5], wb.y, qpacc);
        qpacc = __builtin_fmaf(q8[6], wb.z, qpacc);
        qpacc = __builtin_fmaf(q8[7], wb.w, qpacc);
    }
    qpacc *= NA;                                   // qp' = c * (qp + b1)

    // w2c packed: wc' = w2[e] * (1/8)*log2e / c = w2[e] * -0.07344288
    u32 wcp[4][2];
    float w2row = w2[lane] * -0.07344288f;
#pragma unroll
    for (int mt = 0; mt < 4; ++mt)
#pragma unroll
        for (int h2 = 0; h2 < 2; ++h2) {
            int e0 = mt * 16 + hi * 4 + h2 * 2;
            u32 lo16 = (u32)f2b(__shfl(w2row, e0));
            u32 hi16 = (u32)f2b(__shfl(w2row, e0 + 1));
            wcp[mt][h2] = (hi16 << 16) | lo16;
        }

    // q pieces for frag build: qv2[ks][j] = q[ks*32 + hi*8 + j]
    float qv2[2][8];
#pragma unroll
    for (int ks = 0; ks < 2; ++ks)
#pragma unroll
        for (int j = 0; j < 8; ++j)
            qv2[ks][j] = q_l[wv * 64 + ks * 32 + hi * 8 + j];

    // A-frags: c * qw'[e = mt*16+lo][dd = ks*32 + hi*8 + j], bf16
    short8 af[4][2];
#pragma unroll
    for (int mt = 0; mt < 4; ++mt) {
        const float* wr = w1 + (mt * 16 + lo) * 192;
#pragma unroll
        for (int ks = 0; ks < 2; ++ks) {
            int dd0 = ks * 32 + hi * 8;
            float4 a0 = *(const float4*)(wr + 128 + dd0);
            float4 a1 = *(const float4*)(wr + 128 + dd0 + 4);
            float4 k0 = *(const float4*)(wr + 64 + dd0);
            float4 k1 = *(const float4*)(wr + 64 + dd0 + 4);
            union { u16 u[8]; short8 s; } cv;
            cv.u[0] = f2b(NA * __builtin_fmaf(qv2[ks][0], a0.x, k0.x));
            cv.u[1] = f2b(NA * __builtin_fmaf(qv2[ks][1], a0.y, k0.y));
            cv.u[2] = f2b(NA * __builtin_fmaf(qv2[ks][2], a0.z, k0.z));
            cv.u[3] = f2b(NA * __builtin_fmaf(qv2[ks][3], a0.w, k0.w));
            cv.u[4] = f2b(NA * __builtin_fmaf(qv2[ks][4], a1.x, k1.x));
            cv.u[5] = f2b(NA * __builtin_fmaf(qv2[ks][5], a1.y, k1.y));
            cv.u[6] = f2b(NA * __builtin_fmaf(qv2[ks][6], a1.z, k1.z));
            cv.u[7] = f2b(NA * __builtin_fmaf(qv2[ks][7], a1.w, k1.w));
            af[mt][ks] = cv.s;
        }
    }

    // rank-1 qp' C-init, loop-invariant (v18-verified)
    floatx4 qpinit[4];
    {
        const floatx4 z = (floatx4){0.f, 0.f, 0.f, 0.f};
        union { u16 u[8]; short8 s; } bb;
#pragma unroll
        for (int i = 0; i < 8; ++i) bb.u[i] = 0;
        bb.u[0] = (hi == 0) ? (u16)0x3F80 : (u16)0;   // bf16 1.0 at k=0
#pragma unroll
        for (int mt = 0; mt < 4; ++mt) {
            float qpv = __shfl(qpacc, mt * 16 + lo);
            union { u16 u[8]; short8 s; } aa;
#pragma unroll
            for (int i = 0; i < 8; ++i) aa.u[i] = 0;
            aa.u[0] = (hi == 0) ? f2b(qpv) : (u16)0;
            qpinit[mt] = __builtin_amdgcn_mfma_f32_16x16x32_bf16(aa.s, bb.s, z, 0, 0, 0);
        }
    }

    // K staging source with col-swizzle pre-applied on the GLOBAL address:
    // lane's LDS slot s = wv*64+lane holds (row = s>>3, col = s&7); it must
    // load global 16B unit (row, col ^ (row&7)). row&7 = lane>>3 here.
    const u16* kg = kb + bh * 65536
                  + (wv * 8 + (lane >> 3)) * 64
                  + (((lane & 7) ^ (lane >> 3)) * 8);
    u16* kstg = kbuf + wv * 512;                   // linear LDS dest (wave-uniform + lane*16B)
    kstage(kg, kstg);                              // stage chunk 0 into kbuf[0]
    kg += 2048;

    // swizzled per-lane read bases: row lo, cols ksw / ksw^4 (rows +16 share lo&7)
    int ksw = hi ^ (lo & 7);
    const u16* kr0 = kbuf + lo * 64 + ksw * 8;
    const u16* kr1 = kbuf + lo * 64 + (ksw ^ 4) * 8;

    // drains chunk-0 staging (vmcnt) + plds zero-init + q_l, block-wide
    __syncthreads();

    float l_run = 0.f;
    floatx4 pvacc = (floatx4){0.f, 0.f, 0.f, 0.f};   // out[q=row 0..3][d = wv*16+col]
    // V^T B-frag base: this wave's d-tile row = wv*16+lo, k-offset hi*8
    const u16* vhp = vthi + bh * 65536 + (wv * 16 + lo) * 1024 + hi * 8;
    short8 bf[2][2];

    for (int g = 0; g < 8; ++g) {
        u16* gw  = plds + (g & 1) * (4 * 528);         // this group's write buffer
        u16* pgw = plds + ((g & 1) ^ 1) * (4 * 528);   // previous group's buffer

        // chunk 4g+0 (kbuf parity 0)
        CHUNK_LOAD(0)
        if (g > 0) { PV_GROUP(pgw) }                   // PV for group g-1
        CHUNK_SCORE(0)
        __syncthreads();
        // chunk 4g+1
        CHUNK_LOAD(1)
        CHUNK_SCORE(1)
        __syncthreads();
        // chunk 4g+2
        CHUNK_LOAD(0)
        CHUNK_SCORE(2)
        __syncthreads();
        // chunk 4g+3
        CHUNK_LOAD(1)
        CHUNK_SCORE(3)
        __syncthreads();
    }

    // trailing PV for group 7 (plds[1]); publishes drained by the loop's last barrier
    PV_GROUP(plds + (4 * 528))

    float l = l_run;
    l += __shfl_xor(l, 1); l += __shfl_xor(l, 2);
    l += __shfl_xor(l, 4); l += __shfl_xor(l, 8);
    if (lane == 0) l_sh[wv] = l;
    __syncthreads();

    if (hi == 0) {                                 // C rows 0..3 live on lanes 0..15
        int b = bh >> 3, h = bh & 7;
#pragma unroll
        for (int q = 0; q < 4; ++q) {
            float outv = pvacc[q] * __builtin_amdgcn_rcpf(l_sh[q]);
            ao[((b * 1024 + qbase + q) * 512) + h * 64 + wv * 16 + lo] = outv;
        }
    }
}
#undef CHUNK_LOAD
#undef CHUNK_SCORE
#undef PV_GROUP

// ---------------------------------------------------------------------------
extern "C" void kernel_launch(void* const* d_in, const int* in_sizes, int n_in,
                              void* d_out, int out_size, void* d_ws, size_t ws_size,
                              hipStream_t stream)
{
    (void)in_sizes; (void)n_in; (void)out_size; (void)ws_size;
    const float* x  = (const float*)d_in[0];
    const float* Wq = (const float*)d_in[1];
    const float* bq = (const float*)d_in[2];
    const float* Wk = (const float*)d_in[3];
    const float* bk = (const float*)d_in[4];
    const float* Wv = (const float*)d_in[5];
    const float* bv = (const float*)d_in[6];
    const float* w1 = (const float*)d_in[7];
    const float* b1 = (const float*)d_in[8];
    const float* w2 = (const float*)d_in[9];
    // d_in[10] = b2: scalar shift of all scores -> softmax-invariant -> unused
    const float* Wo = (const float*)d_in[11];
    const float* bo = (const float*)d_in[12];

    char* ws = (char*)d_ws;
    float* q_ws = (float*)(ws);               // 4 MB fp32 (b,h,c,d)
    u16*   k_ws = (u16*)(ws + (4u << 20));    // 2 MB bf16 (b,h,c,d)
    u16*   vthi = (u16*)(ws + (6u << 20));    // 2 MB bf16 V^T hi (b,h,d,c)
    u16*   vtlo = (u16*)(ws + (8u << 20));    // 2 MB bf16 V^T lo (b,h,d,c) (MUST stay vthi+2MB)
    float* a_ws = (float*)(ws + (10u << 20)); // 4 MB fp32 (b,c,D)

    dim3 blk(256);
    hipLaunchKernelGGL(gemm_qkv, dim3(32, 24), blk, 0, stream,
                       x, Wq, Wk, Wv, bq, bk, bv, q_ws, k_ws, vthi, vtlo);
    hipLaunchKernelGGL(attn24, dim3(4096), blk, 0, stream,
                       q_ws, k_ws, vthi, vtlo, w1, b1, w2, a_ws);
    hipLaunchKernelGGL(gemm_out, dim3(32, 8), blk, 0, stream, a_ws, Wo, bo, (float*)d_out);
}